// Round 2
// baseline (336.780 us; speedup 1.0000x reference)
//
#include <hip/hip_runtime.h>
#include <hip/hip_bf16.h>

// ---------------- problem constants ----------------
#define BATCH   4
#define SEQ     2048
#define DMODEL  512
#define NHEADS  8
#define HEADDIM 64
#define MTOT    (BATCH*SEQ)      // 8192 rows
#define NX      (MTOT*DMODEL)    // 4194304 x elements
#define NW      (DMODEL*DMODEL)  // 262144 weight elements
#define QTILE   64               // q rows per block (4 q-waves x 16)
#define KTILE   32               // k rows per tile
#define NKT_G   32               // tiles per k-group (2 groups cover SEQ)

#define LOG2E   1.4426950408889634f
#define SCL2    0.18033688011112042f      // 0.125 * log2e
#define SHIFT   14.426950408889634f       // overflow headroom shift
// ---------------------------------------------------

typedef unsigned short u16;
typedef __bf16 bf16x8 __attribute__((ext_vector_type(8)));
typedef float  f32x4  __attribute__((ext_vector_type(4)));
typedef unsigned short u16x4 __attribute__((ext_vector_type(4)));
typedef unsigned u32x2 __attribute__((ext_vector_type(2)));

#define MFMA(a,b,c) __builtin_amdgcn_mfma_f32_16x16x32_bf16(a,b,c,0,0,0)

__device__ __forceinline__ u16 f2bf(float f) {
    unsigned u = __float_as_uint(f);
    u += 0x7FFFu + ((u >> 16) & 1u);   // RNE
    return (u16)(u >> 16);
}
__device__ __forceinline__ unsigned pk_bf16(float a, float b) {
    union { __hip_bfloat162 h; unsigned u; } cv;
    cv.h = __float22bfloat162_rn(make_float2(a, b));
    return cv.u;
}
__device__ __forceinline__ void gll16(const void* g, void* l) {
    __builtin_amdgcn_global_load_lds((const __attribute__((address_space(1))) void*)g,
                                     (__attribute__((address_space(3))) void*)l, 16, 0, 0);
}
__device__ __forceinline__ void gll4(const void* g, void* l) {
    __builtin_amdgcn_global_load_lds((const __attribute__((address_space(1))) void*)g,
                                     (__attribute__((address_space(3))) void*)l, 4, 0, 0);
}

// ---------------- kernel 0: fp32 -> bf16 converts + rope cos/sin table ----------------
#define NCVT4 ((NX + 4*NW)/4)    // 1310720 float4 groups
__global__ __launch_bounds__(256) void cvt_rope_kernel(
    const float* __restrict__ x,
    const float* __restrict__ wq, const float* __restrict__ wk,
    const float* __restrict__ wv, const float* __restrict__ wo,
    u16* __restrict__ xbf,
    u16* __restrict__ wqbf, u16* __restrict__ wkbf,
    u16* __restrict__ wvbf, u16* __restrict__ wobf,
    float2* __restrict__ cst)
{
    int i4 = blockIdx.x * 256 + threadIdx.x;
    if (i4 < NCVT4) {
        int i = i4 * 4;
        const float* s; u16* d; int o;
        if (i < NX) { s = x; d = xbf; o = i; }
        else {
            int j = i - NX;
            int r = j >> 18;            // NW = 2^18
            o = j & (NW - 1);
            s = (r == 0) ? wq : (r == 1) ? wk : (r == 2) ? wv : wo;
            d = (r == 0) ? wqbf : (r == 1) ? wkbf : (r == 2) ? wvbf : wobf;
        }
        float4 v = *(const float4*)(s + o);
        u16x4 u = { f2bf(v.x), f2bf(v.y), f2bf(v.z), f2bf(v.w) };
        *(u16x4*)(d + o) = u;
    } else {
        int r = i4 - NCVT4;             // [0, 16384)
        if (r < SEQ * 32 / 4) {
            int idx = r * 4;
            int s  = idx >> 5;
            int p0 = idx & 31;
#pragma unroll
            for (int t = 0; t < 4; ++t) {
                int p = p0 + t;
                float inv = __expf(-0.5756462732485115f * (float)(p & 15));
                float ang = (float)s * inv;
                cst[idx + t] = make_float2(cosf(ang), sinf(ang));
            }
        }
    }
}

// ---------------- kernel 1: fused QKV projection + RoPE (128x128, LDS-staged) ----------------
#define TP 136   // LDS tile row stride (u16 elems)
__global__ __launch_bounds__(256) void qkv_kernel(
    const u16* __restrict__ x,
    const u16* __restrict__ Wq, const float* __restrict__ bq,
    const u16* __restrict__ Wk, const float* __restrict__ bk,
    const u16* __restrict__ Wv, const float* __restrict__ bv,
    const float* __restrict__ cstf,     // cst as float*, {cos,sin} interleaved
    u16* __restrict__ qws, u16* __restrict__ kws, u16* __restrict__ vtws)
{
    __shared__ alignas(16) u16 smem[128 * TP];   // 34816 B; As/Bs alias the front
    u16* As = smem;            // x tile   128x64
    u16* Bs = smem + 8192;     // W tile   128x64

    const int m0 = blockIdx.x * 128;         // x-row tile
    const int n0 = blockIdx.y * 128;         // col tile over 1536
    const int tid  = threadIdx.x;
    const int w    = tid >> 6;
    const int lane = tid & 63;
    const int quad = lane >> 4;
    const int l16  = lane & 15;
    const int wm = w & 1, wn = w >> 1;

    const int sec = n0 >> 9;                 // 0=Q 1=K 2=V
    const int oc0 = n0 & 511;
    const u16*   Wm = (sec == 0) ? Wq : (sec == 1 ? Wk : Wv);
    const float* bb = (sec == 0) ? bq : (sec == 1 ? bk : bv);

    const int xb = (sec < 2) ? wn : wm;      // x-row fragment base
    const int wb = (sec < 2) ? wm : wn;      // W-row fragment base

    f32x4 acc[4][4] = {};

    for (int kb = 0; kb < 8; ++kb) {
#pragma unroll
        for (int it = 0; it < 4; ++it) {
            const int s   = it * 256 + tid;
            const int row = s >> 3;
            const int cb  = s & 7;
            const int gcol = kb * 64 + (((cb ^ (row & 7))) << 3);
            gll16(x  + (m0  + row) * 512 + gcol, &As[s * 8]);
            gll16(Wm + (oc0 + row) * 512 + gcol, &Bs[s * 8]);
        }
        __syncthreads();

#pragma unroll
        for (int ks = 0; ks < 2; ++ks) {
            bf16x8 xf[4], wf[4];
#pragma unroll
            for (int t = 0; t < 4; ++t) {
                const int xrow = xb * 64 + t * 16 + l16;
                const int wrow = wb * 64 + t * 16 + l16;
                xf[t] = *(const bf16x8*)&As[xrow * 64 + (((ks * 4 + quad) ^ (xrow & 7)) << 3)];
                wf[t] = *(const bf16x8*)&Bs[wrow * 64 + (((ks * 4 + quad) ^ (wrow & 7)) << 3)];
            }
            if (sec < 2) {
#pragma unroll
                for (int tm = 0; tm < 4; ++tm)
#pragma unroll
                    for (int tn = 0; tn < 4; ++tn)
                        acc[tm][tn] = MFMA(wf[tm], xf[tn], acc[tm][tn]);  // C row=d, col=s
            } else {
#pragma unroll
                for (int tm = 0; tm < 4; ++tm)
#pragma unroll
                    for (int tn = 0; tn < 4; ++tn)
                        acc[tm][tn] = MFMA(xf[tm], wf[tn], acc[tm][tn]);  // C row=s, col=d
            }
        }
        __syncthreads();
    }

    if (sec < 2) {
        // ---- Q/K epilogue: C row = head-dim, col = s. rope fully in-register ----
#pragma unroll
        for (int tm = 0; tm < 4; ++tm) {
            const int dls = wm * 64 + tm * 16 + quad * 4;         // local d base (mult of 4)
            const float4 bv4 = *(const float4*)&bb[oc0 + dls];
            const int pbase = ((oc0 + dls) & 63) >> 1;            // rope pair idx (even)
#pragma unroll
            for (int tn = 0; tn < 4; ++tn) {
                const int sl = wn * 64 + tn * 16 + l16;           // local s
                const int sg = (m0 + sl) & 2047;                  // seq pos
                const float4 cs = *(const float4*)&cstf[sg * 64 + pbase * 2]; // c0,s0,c1,s1
                const float v0 = acc[tm][tn][0] + bv4.x;
                const float v1 = acc[tm][tn][1] + bv4.y;
                const float v2 = acc[tm][tn][2] + bv4.z;
                const float v3 = acc[tm][tn][3] + bv4.w;
                const float r0 = v0 * cs.x - v1 * cs.y;
                const float r1 = v1 * cs.x + v0 * cs.y;
                const float r2 = v2 * cs.z - v3 * cs.w;
                const float r3 = v3 * cs.z + v2 * cs.w;
                u32x2 pv = { pk_bf16(r0, r1), pk_bf16(r2, r3) };
                *(u32x2*)&smem[sl * TP + dls] = pv;
            }
        }
        __syncthreads();
        u16* dst0 = (sec == 0) ? qws : kws;
#pragma unroll
        for (int i = 0; i < 8; ++i) {
            const int c   = i * 256 + tid;       // [0, 2048)
            const int sl  = c >> 4;              // local s row
            const int d8  = (c & 15) * 8;        // 8-dim chunk
            const int gcol = oc0 + d8;
            const int hh  = gcol >> 6;
            const int dh  = gcol & 63;
            const int sgl = m0 + sl;
            const int bi  = sgl >> 11;
            const int s   = sgl & 2047;
            u16* dst = dst0 + (size_t)(bi * NHEADS + hh) * (SEQ * HEADDIM)
                            + (size_t)s * HEADDIM + dh;
            *(bf16x8*)dst = *(const bf16x8*)&smem[sl * TP + d8];
        }
    } else {
        // ---- V epilogue: C row = s, col = out-col d. LDS transpose T[d][s] ----
#pragma unroll
        for (int tm = 0; tm < 4; ++tm) {
            const int row_l = wm * 64 + tm * 16 + quad * 4;      // local s rows
#pragma unroll
            for (int tn = 0; tn < 4; ++tn) {
                const int col_l = wn * 64 + tn * 16 + l16;       // local out-col
                const float bval = bb[oc0 + col_l];
                u32x2 pv = { pk_bf16(acc[tm][tn][0] + bval, acc[tm][tn][1] + bval),
                             pk_bf16(acc[tm][tn][2] + bval, acc[tm][tn][3] + bval) };
                *(u32x2*)&smem[col_l * TP + row_l] = pv;
            }
        }
        __syncthreads();
        const int bi  = m0 >> 11;
        const int sgb = m0 & 2047;
#pragma unroll
        for (int i = 0; i < 8; ++i) {
            const int c    = i * 256 + tid;      // [0, 2048)
            const int col  = c >> 4;             // local out-col
            const int sc8  = (c & 15) * 8;       // s-chunk
            const int gcol = oc0 + col;
            const int hh   = gcol >> 6;
            const int d    = gcol & 63;
            u16* dst = vtws + (size_t)(bi * NHEADS + hh) * (SEQ * HEADDIM)
                            + (size_t)d * SEQ + sgb + sc8;
            *(bf16x8*)dst = *(const bf16x8*)&smem[col * TP + sc8];
        }
    }
}

// ---------------- kernel 2: flash attention, in-block K-split, in-register P ----------------
// grid: (SEQ/QTILE, B*H) = (32, 32). block 512 = 8 waves.
// wave w: qw = w&3 owns q rows; kg = w>>2 owns half the k range.
// Swapped QK^T: MFMA(K, Q) -> P[k=nt*16+quad*4+r][q=l16] lane-local. Softmax/bias
// applied in-register (vq scalar per lane, per-k ids via broadcast int4 reads).
// P redistributed to the PV A-fragment layout with 3 shfl_xor rounds (16/32/48) —
// no P LDS tile, no lgkm drain, no P bank conflicts. LDS 34.3 KB -> 4 blocks/CU.
__global__ __launch_bounds__(512, 8) void attn_kernel(
    const u16* __restrict__ qws, const u16* __restrict__ kws,
    const u16* __restrict__ vtl,
    const int* __restrict__ vids, const float* __restrict__ mask,
    const float* __restrict__ u_same, const float* __restrict__ u_cross,
    u16* __restrict__ attn)
{
    // LDS map (u16 units):
    //   [    0,  8192): K tiles   [grp][buf][32*64]
    //   [ 8192, 16384): V^T tiles [grp][buf][64*32]
    // combine phase aliases the front as float co[64][65] (16640 B).
    __shared__ alignas(16) u16 smem[16384];
    __shared__ int   bidm[2][2][KTILE];
    __shared__ float bmkm[2][2][KTILE];
    __shared__ float comb_li2[2][QTILE];

    const int bh = blockIdx.y;
    const int b  = bh >> 3;
    const int h  = bh & 7;
    const int q0 = blockIdx.x * QTILE;

    const int tid  = threadIdx.x;
    const int w    = tid >> 6;                // 0..7
    const int lane = tid & 63;
    const int quad = lane >> 4;
    const int l16  = lane & 15;
    const int qw   = w & 3;                   // q sub-tile
    const int kg   = w >> 2;                  // k group
    const int tl   = tid & 255;               // thread index within k group

    const float us2 = u_same[h]  * LOG2E;
    const float uc2 = u_cross[h] * LOG2E;
    const size_t tb = (size_t)bh * (SEQ * HEADDIM);

    const int qr = q0 + qw * 16 + l16;
    const bf16x8 aq0 = *(const bf16x8*)(qws + tb + qr * HEADDIM + quad * 8);
    const bf16x8 aq1 = *(const bf16x8*)(qws + tb + qr * HEADDIM + 32 + quad * 8);

    const int vq = vids[b * SEQ + q0 + qw * 16 + l16];   // this lane's q variate id

    float li = 0.f;
    f32x4 o[4] = {};

    // staging geometry (per k group: 256 threads stage one K + one V^T tile)
    const int srow  = tl >> 3;                // K tile row (k), 0..31
    const int scb   = tl & 7;
    const int soff  = ((scb ^ (srow & 7)) << 3);
    const int vrow  = tl >> 2;                // V^T tile row (d), 0..63
    const int vcb   = (tl & 3) ^ ((vrow >> 1) & 3);   // bank-spread swizzle
    const int soffv = (vcb << 3);
    const int kbase = kg * 2 * 2048;          // + cur*2048

    auto stage = [&](int t, int nb) {
        const int k0 = (kg * NKT_G + t) * KTILE;
        gll16(kws + tb + (size_t)(k0 + srow) * HEADDIM + soff,
              &smem[kbase + nb * 2048 + tl * 8]);
        gll16(vtl + tb + (size_t)vrow * SEQ + k0 + soffv,
              &smem[8192 + kbase + nb * 2048 + tl * 8]);
        if (tl < KTILE) {
            gll4(vids + b * SEQ + k0 + tl, &bidm[kg][nb][0]);
            gll4(mask + b * SEQ + k0 + tl, &bmkm[kg][nb][0]);
        }
    };

    auto body = [&](const int cur) {   // cur literal at call sites
        const u16* kb_b = &smem[kbase + cur * 2048];
        const u16* vb_b = &smem[8192 + kbase + cur * 2048];
        unsigned x0, x1, y0, y1;       // packed bf16 P words, nt0 (x) / nt1 (y)
#pragma unroll
        for (int nt = 0; nt < 2; ++nt) {
            const int krow = nt * 16 + l16;
            const int r7   = krow & 7;
            const bf16x8 kb0 = *(const bf16x8*)&kb_b[krow * 64 + ((quad ^ r7) << 3)];
            const bf16x8 kb1 = *(const bf16x8*)&kb_b[krow * 64 + ((quad ^ r7 ^ 4) << 3)];
            f32x4 sc = {};
            sc = MFMA(kb0, aq0, sc);   // swapped: C row = k, col = q(l16)
            sc = MFMA(kb1, aq1, sc);
            const int kk = nt * 16 + quad * 4;     // this lane's 4 k rows
            const int4   kv4 = *(const int4*)&bidm[kg][cur][kk];    // broadcast reads
            const float4 mk4 = *(const float4*)&bmkm[kg][cur][kk];
            const int   kvr[4] = { kv4.x, kv4.y, kv4.z, kv4.w };
            const float mkr[4] = { mk4.x, mk4.y, mk4.z, mk4.w };
            float p[4];
#pragma unroll
            for (int r = 0; r < 4; ++r) {
                const float mdl = fmaf(mkr[r], 1.4426950408889634e9f,
                                       -1.4426950408889634e9f - SHIFT);
                const float sel = (kvr[r] == vq) ? (us2 + mdl) : (uc2 + mdl);
                p[r] = __builtin_amdgcn_exp2f(fmaf(sc[r], SCL2, sel));
                li += p[r];
            }
            if (nt == 0) { x0 = pk_bf16(p[0], p[1]); x1 = pk_bf16(p[2], p[3]); }
            else         { y0 = pk_bf16(p[0], p[1]); y1 = pk_bf16(p[2], p[3]); }
        }

        // redistribute P to PV A-fragment layout: lane needs P[q=l16][8*quad .. 8*quad+7]
        const bool qlo = (quad < 2);
        const bool qod = (quad & 1);
        const unsigned a0 = qlo ? x0 : y0, a1 = qlo ? x1 : y1;
        const unsigned r0 = __shfl_xor((int)a0, 16), r1 = __shfl_xor((int)a1, 16);
        const unsigned b0 = qod ? x0 : y0, b1 = qod ? x1 : y1;
        const unsigned s0 = __shfl_xor((int)b0, 32), s1 = __shfl_xor((int)b1, 32);
        const unsigned c0 = qod ? y0 : x0, c1 = qod ? y1 : x1;
        const unsigned t0 = __shfl_xor((int)c0, 48), t1 = __shfl_xor((int)c1, 48);
        union { unsigned u[4]; bf16x8 v; } ap;
        ap.u[0] = (quad == 0) ? x0 : (quad == 1) ? t0 : (quad == 2) ? s0 : r0;
        ap.u[1] = (quad == 0) ? x1 : (quad == 1) ? t1 : (quad == 2) ? s1 : r1;
        ap.u[2] = (quad == 0) ? r0 : (quad == 1) ? s0 : (quad == 2) ? t0 : y0;
        ap.u[3] = (quad == 0) ? r1 : (quad == 1) ? s1 : (quad == 2) ? t1 : y1;

#pragma unroll
        for (int nt = 0; nt < 4; ++nt) {
            const int vr = nt * 16 + l16;
            const bf16x8 vb0 = *(const bf16x8*)&vb_b[vr * 32 + (((quad ^ ((vr >> 1) & 3))) << 3)];
            o[nt] = MFMA(ap.v, vb0, o[nt]);
        }
    };

    stage(0, 0);
    for (int t = 0; t < NKT_G; t += 2) {
        __syncthreads();
        stage(t + 1, 1);
        body(0);
        __syncthreads();
        if (t + 2 < NKT_G) stage(t + 2, 0);
        body(1);
    }

    // ---- combine the two k-groups' partials through LDS ----
    float liq = li + __shfl_xor(li, 16);
    liq += __shfl_xor(liq, 32);               // full kg-partial row sum, q = l16
    __syncthreads();
    float* co = (float*)smem;                 // [64][65] f32, aliases K/V buffers
    if (quad == 0) comb_li2[kg][qw * 16 + l16] = liq;
    if (kg == 1) {
#pragma unroll
        for (int nt = 0; nt < 4; ++nt)
#pragma unroll
            for (int r = 0; r < 4; ++r)
                co[(qw * 16 + quad * 4 + r) * 65 + nt * 16 + l16] = o[nt][r];
    }
    __syncthreads();
    if (kg == 0) {
#pragma unroll
        for (int r = 0; r < 4; ++r) {
            const int qloc = qw * 16 + quad * 4 + r;
            const float lt = comb_li2[0][qloc] + comb_li2[1][qloc];
            const float inv = 1.0f / lt;
            const int R  = q0 + qloc;
            const int rb = (b * SEQ + R) * DMODEL + h * HEADDIM;
#pragma unroll
            for (int nt = 0; nt < 4; ++nt)
                attn[rb + nt * 16 + l16] =
                    f2bf((o[nt][r] + co[qloc * 65 + nt * 16 + l16]) * inv);
        }
    }
}

// ---------------- kernel 3: output projection (swapped A/B, LDS store, fp32 out) ----------------
__global__ __launch_bounds__(256) void proj_kernel(
    const u16* __restrict__ a, const u16* __restrict__ Wo,
    const float* __restrict__ bo, float* __restrict__ out)
{
    __shared__ alignas(16) u16 psm[132 * 64 * 2];    // 33792 B; As/Bs alias front, Lp aliases all
    u16* As = psm;
    u16* Bs = psm + 8192;
    float* Lp = (float*)psm;                         // 64 x 132 f32 tile

    const int m0 = blockIdx.x * 128;                 // attn-row tile
    const int n0 = blockIdx.y * 128;                 // out-col strip
    const int tid  = threadIdx.x;
    const int w    = tid >> 6;
    const int lane = tid & 63;
    const int quad = lane >> 4;
    const int l16  = lane & 15;
    const int wm = w & 1, wn = w >> 1;               // wm: W-col tile, wn: s tile

    f32x4 acc[4][4] = {};

    for (int kb = 0; kb < 8; ++kb) {
#pragma unroll
        for (int it = 0; it < 4; ++it) {
            const int s   = it * 256 + tid;
            const int row = s >> 3;
            const int cb  = s & 7;
            const int gcol = kb * 64 + (((cb ^ (row & 7))) << 3);
            gll16(a  + (m0 + row) * 512 + gcol, &As[s * 8]);
            gll16(Wo + (n0 + row) * 512 + gcol, &Bs[s * 8]);
        }
        __syncthreads();

#pragma unroll
        for (int ks = 0; ks < 2; ++ks) {
            bf16x8 af[4], wf[4];
#pragma unroll
            for (int t = 0; t < 4; ++t) {
                const int arow = wn * 64 + t * 16 + l16;
                const int wrow = wm * 64 + t * 16 + l16;
                af[t] = *(const bf16x8*)&As[arow * 64 + (((ks * 4 + quad) ^ (arow & 7)) << 3)];
                wf[t] = *(const bf16x8*)&Bs[wrow * 64 + (((ks * 4 + quad) ^ (wrow & 7)) << 3)];
            }
#pragma unroll
            for (int tm = 0; tm < 4; ++tm)
#pragma unroll
                for (int tn = 0; tn < 4; ++tn)
                    acc[tm][tn] = MFMA(wf[tm], af[tn], acc[tm][tn]);  // C row=d, col=s
        }
        __syncthreads();
    }

    // two phases by s-half: waves wn==hph write Lp[s2][d], all threads store coalesced
#pragma unroll
    for (int hph = 0; hph < 2; ++hph) {
        if (wn == hph) {
#pragma unroll
            for (int tm = 0; tm < 4; ++tm) {
                const int dls = wm * 64 + tm * 16 + quad * 4;
                const float4 bv4 = *(const float4*)&bo[n0 + dls];
#pragma unroll
                for (int tn = 0; tn < 4; ++tn) {
                    const int s2 = tn * 16 + l16;            // [0,64)
                    float4 v = { acc[tm][tn][0] + bv4.x, acc[tm][tn][1] + bv4.y,
                                 acc[tm][tn][2] + bv4.z, acc[tm][tn][3] + bv4.w };
                    *(float4*)&Lp[s2 * 132 + dls] = v;
                }
            }
        }
        __syncthreads();
#pragma unroll
        for (int i = 0; i < 8; ++i) {
            const int c  = i * 256 + tid;        // [0,2048)
            const int s2 = c >> 5;               // [0,64)
            const int dq = (c & 31) * 4;         // [0,128)
            float4 v = *(const float4*)&Lp[s2 * 132 + dq];
            *(float4*)&out[(size_t)(m0 + hph * 64 + s2) * 512 + n0 + dq] = v;
        }
        __syncthreads();
    }
}

// ---------------- launch ----------------
extern "C" void kernel_launch(void* const* d_in, const int* in_sizes, int n_in,
                              void* d_out, int out_size, void* d_ws, size_t ws_size,
                              hipStream_t stream) {
    const float* x    = (const float*)d_in[0];
    const int*   vids = (const int*)d_in[1];
    const float* mask = (const float*)d_in[2];
    const float* Wq = (const float*)d_in[3];
    const float* bq = (const float*)d_in[4];
    const float* Wk = (const float*)d_in[5];
    const float* bk = (const float*)d_in[6];
    const float* Wv = (const float*)d_in[7];
    const float* bv = (const float*)d_in[8];
    const float* Wo = (const float*)d_in[9];
    const float* bo = (const float*)d_in[10];
    const float* usame  = (const float*)d_in[11];
    const float* ucross = (const float*)d_in[12];
    float* out = (float*)d_out;

    u16* xbf  = (u16*)d_ws;                 // 8 MB; reused as attention output
    u16* wqbf = xbf + NX;                   // 512 KB each
    u16* wkbf = wqbf + NW;
    u16* wvbf = wkbf + NW;
    u16* wobf = wvbf + NW;
    float2* cst = (float2*)(wobf + NW);     // 512 KB
    u16* qws  = (u16*)(cst + SEQ * 32);     // 8 MB each
    u16* kws  = qws + (size_t)BATCH * NHEADS * SEQ * HEADDIM;
    u16* vtws = kws + (size_t)BATCH * NHEADS * SEQ * HEADDIM;
    u16* attn = xbf;

    cvt_rope_kernel<<<(NCVT4 + SEQ * 32 / 4 + 255) / 256, 256, 0, stream>>>(
        x, Wq, Wk, Wv, Wo, xbf, wqbf, wkbf, wvbf, wobf, cst);

    dim3 g1(MTOT / 128, 3 * DMODEL / 128);  // 64 x 12
    qkv_kernel<<<g1, 256, 0, stream>>>(xbf, wqbf, bq, wkbf, bk, wvbf, bv,
                                       (const float*)cst, qws, kws, vtws);

    dim3 g2(SEQ / QTILE, BATCH * NHEADS);   // 32 x 32
    attn_kernel<<<g2, 512, 0, stream>>>(qws, kws, vtws, vids, mask,
                                        usame, ucross, attn);

    dim3 g3(MTOT / 128, DMODEL / 128);      // 64 x 4
    proj_kernel<<<g3, 256, 0, stream>>>(attn, wobf, bo, out);
}

// Round 3
// 207.472 us; speedup vs baseline: 1.6233x; 1.6233x over previous
//
#include <hip/hip_runtime.h>
#include <hip/hip_bf16.h>

// ---------------- problem constants ----------------
#define BATCH   4
#define SEQ     2048
#define DMODEL  512
#define NHEADS  8
#define HEADDIM 64
#define MTOT    (BATCH*SEQ)      // 8192 rows
#define NX      (MTOT*DMODEL)    // 4194304 x elements
#define NW      (DMODEL*DMODEL)  // 262144 weight elements
#define QTILE   64               // q rows per block (4 q-waves x 16)
#define KTILE   32               // k rows per tile
#define NKT_G   32               // tiles per k-group (2 groups cover SEQ)

#define LOG2E   1.4426950408889634f
#define SCL2    0.18033688011112042f      // 0.125 * log2e
#define SHIFT   14.426950408889634f       // overflow headroom shift
// ---------------------------------------------------

typedef unsigned short u16;
typedef __bf16 bf16x8 __attribute__((ext_vector_type(8)));
typedef float  f32x4  __attribute__((ext_vector_type(4)));
typedef unsigned short u16x4 __attribute__((ext_vector_type(4)));
typedef unsigned u32x2 __attribute__((ext_vector_type(2)));

#define MFMA(a,b,c) __builtin_amdgcn_mfma_f32_16x16x32_bf16(a,b,c,0,0,0)

__device__ __forceinline__ u16 f2bf(float f) {
    unsigned u = __float_as_uint(f);
    u += 0x7FFFu + ((u >> 16) & 1u);   // RNE
    return (u16)(u >> 16);
}
__device__ __forceinline__ unsigned pk_bf16(float a, float b) {
    union { __hip_bfloat162 h; unsigned u; } cv;
    cv.h = __float22bfloat162_rn(make_float2(a, b));
    return cv.u;
}
__device__ __forceinline__ void gll16(const void* g, void* l) {
    __builtin_amdgcn_global_load_lds((const __attribute__((address_space(1))) void*)g,
                                     (__attribute__((address_space(3))) void*)l, 16, 0, 0);
}
__device__ __forceinline__ void gll4(const void* g, void* l) {
    __builtin_amdgcn_global_load_lds((const __attribute__((address_space(1))) void*)g,
                                     (__attribute__((address_space(3))) void*)l, 4, 0, 0);
}

// ---------------- kernel 0: fp32 -> bf16 converts + rope cos/sin table ----------------
#define NCVT4 ((NX + 4*NW)/4)    // 1310720 float4 groups
__global__ __launch_bounds__(256) void cvt_rope_kernel(
    const float* __restrict__ x,
    const float* __restrict__ wq, const float* __restrict__ wk,
    const float* __restrict__ wv, const float* __restrict__ wo,
    u16* __restrict__ xbf,
    u16* __restrict__ wqbf, u16* __restrict__ wkbf,
    u16* __restrict__ wvbf, u16* __restrict__ wobf,
    float2* __restrict__ cst)
{
    int i4 = blockIdx.x * 256 + threadIdx.x;
    if (i4 < NCVT4) {
        int i = i4 * 4;
        const float* s; u16* d; int o;
        if (i < NX) { s = x; d = xbf; o = i; }
        else {
            int j = i - NX;
            int r = j >> 18;            // NW = 2^18
            o = j & (NW - 1);
            s = (r == 0) ? wq : (r == 1) ? wk : (r == 2) ? wv : wo;
            d = (r == 0) ? wqbf : (r == 1) ? wkbf : (r == 2) ? wvbf : wobf;
        }
        float4 v = *(const float4*)(s + o);
        u16x4 u = { f2bf(v.x), f2bf(v.y), f2bf(v.z), f2bf(v.w) };
        *(u16x4*)(d + o) = u;
    } else {
        int r = i4 - NCVT4;             // [0, 16384)
        if (r < SEQ * 32 / 4) {
            int idx = r * 4;
            int s  = idx >> 5;
            int p0 = idx & 31;
#pragma unroll
            for (int t = 0; t < 4; ++t) {
                int p = p0 + t;
                float inv = __expf(-0.5756462732485115f * (float)(p & 15));
                float ang = (float)s * inv;
                cst[idx + t] = make_float2(cosf(ang), sinf(ang));
            }
        }
    }
}

// ---------------- kernel 1: fused QKV projection + RoPE (128x128, LDS-staged) ----------------
#define TP 136   // LDS tile row stride (u16 elems)
__global__ __launch_bounds__(256) void qkv_kernel(
    const u16* __restrict__ x,
    const u16* __restrict__ Wq, const float* __restrict__ bq,
    const u16* __restrict__ Wk, const float* __restrict__ bk,
    const u16* __restrict__ Wv, const float* __restrict__ bv,
    const float* __restrict__ cstf,     // cst as float*, {cos,sin} interleaved
    u16* __restrict__ qws, u16* __restrict__ kws, u16* __restrict__ vtws)
{
    __shared__ alignas(16) u16 smem[128 * TP];   // 34816 B; As/Bs alias the front
    u16* As = smem;            // x tile   128x64
    u16* Bs = smem + 8192;     // W tile   128x64

    const int m0 = blockIdx.x * 128;         // x-row tile
    const int n0 = blockIdx.y * 128;         // col tile over 1536
    const int tid  = threadIdx.x;
    const int w    = tid >> 6;
    const int lane = tid & 63;
    const int quad = lane >> 4;
    const int l16  = lane & 15;
    const int wm = w & 1, wn = w >> 1;

    const int sec = n0 >> 9;                 // 0=Q 1=K 2=V
    const int oc0 = n0 & 511;
    const u16*   Wm = (sec == 0) ? Wq : (sec == 1 ? Wk : Wv);
    const float* bb = (sec == 0) ? bq : (sec == 1 ? bk : bv);

    const int xb = (sec < 2) ? wn : wm;      // x-row fragment base
    const int wb = (sec < 2) ? wm : wn;      // W-row fragment base

    f32x4 acc[4][4] = {};

    for (int kb = 0; kb < 8; ++kb) {
#pragma unroll
        for (int it = 0; it < 4; ++it) {
            const int s   = it * 256 + tid;
            const int row = s >> 3;
            const int cb  = s & 7;
            const int gcol = kb * 64 + (((cb ^ (row & 7))) << 3);
            gll16(x  + (m0  + row) * 512 + gcol, &As[s * 8]);
            gll16(Wm + (oc0 + row) * 512 + gcol, &Bs[s * 8]);
        }
        __syncthreads();

#pragma unroll
        for (int ks = 0; ks < 2; ++ks) {
            bf16x8 xf[4], wf[4];
#pragma unroll
            for (int t = 0; t < 4; ++t) {
                const int xrow = xb * 64 + t * 16 + l16;
                const int wrow = wb * 64 + t * 16 + l16;
                xf[t] = *(const bf16x8*)&As[xrow * 64 + (((ks * 4 + quad) ^ (xrow & 7)) << 3)];
                wf[t] = *(const bf16x8*)&Bs[wrow * 64 + (((ks * 4 + quad) ^ (wrow & 7)) << 3)];
            }
            if (sec < 2) {
#pragma unroll
                for (int tm = 0; tm < 4; ++tm)
#pragma unroll
                    for (int tn = 0; tn < 4; ++tn)
                        acc[tm][tn] = MFMA(wf[tm], xf[tn], acc[tm][tn]);  // C row=d, col=s
            } else {
#pragma unroll
                for (int tm = 0; tm < 4; ++tm)
#pragma unroll
                    for (int tn = 0; tn < 4; ++tn)
                        acc[tm][tn] = MFMA(xf[tm], wf[tn], acc[tm][tn]);  // C row=s, col=d
            }
        }
        __syncthreads();
    }

    if (sec < 2) {
        // ---- Q/K epilogue: C row = head-dim, col = s. rope fully in-register ----
#pragma unroll
        for (int tm = 0; tm < 4; ++tm) {
            const int dls = wm * 64 + tm * 16 + quad * 4;         // local d base (mult of 4)
            const float4 bv4 = *(const float4*)&bb[oc0 + dls];
            const int pbase = ((oc0 + dls) & 63) >> 1;            // rope pair idx (even)
#pragma unroll
            for (int tn = 0; tn < 4; ++tn) {
                const int sl = wn * 64 + tn * 16 + l16;           // local s
                const int sg = (m0 + sl) & 2047;                  // seq pos
                const float4 cs = *(const float4*)&cstf[sg * 64 + pbase * 2]; // c0,s0,c1,s1
                const float v0 = acc[tm][tn][0] + bv4.x;
                const float v1 = acc[tm][tn][1] + bv4.y;
                const float v2 = acc[tm][tn][2] + bv4.z;
                const float v3 = acc[tm][tn][3] + bv4.w;
                const float r0 = v0 * cs.x - v1 * cs.y;
                const float r1 = v1 * cs.x + v0 * cs.y;
                const float r2 = v2 * cs.z - v3 * cs.w;
                const float r3 = v3 * cs.z + v2 * cs.w;
                u32x2 pv = { pk_bf16(r0, r1), pk_bf16(r2, r3) };
                *(u32x2*)&smem[sl * TP + dls] = pv;
            }
        }
        __syncthreads();
        u16* dst0 = (sec == 0) ? qws : kws;
#pragma unroll
        for (int i = 0; i < 8; ++i) {
            const int c   = i * 256 + tid;       // [0, 2048)
            const int sl  = c >> 4;              // local s row
            const int d8  = (c & 15) * 8;        // 8-dim chunk
            const int gcol = oc0 + d8;
            const int hh  = gcol >> 6;
            const int dh  = gcol & 63;
            const int sgl = m0 + sl;
            const int bi  = sgl >> 11;
            const int s   = sgl & 2047;
            u16* dst = dst0 + (size_t)(bi * NHEADS + hh) * (SEQ * HEADDIM)
                            + (size_t)s * HEADDIM + dh;
            *(bf16x8*)dst = *(const bf16x8*)&smem[sl * TP + d8];
        }
    } else {
        // ---- V epilogue: C row = s, col = out-col d. LDS transpose T[d][s] ----
#pragma unroll
        for (int tm = 0; tm < 4; ++tm) {
            const int row_l = wm * 64 + tm * 16 + quad * 4;      // local s rows
#pragma unroll
            for (int tn = 0; tn < 4; ++tn) {
                const int col_l = wn * 64 + tn * 16 + l16;       // local out-col
                const float bval = bb[oc0 + col_l];
                u32x2 pv = { pk_bf16(acc[tm][tn][0] + bval, acc[tm][tn][1] + bval),
                             pk_bf16(acc[tm][tn][2] + bval, acc[tm][tn][3] + bval) };
                *(u32x2*)&smem[col_l * TP + row_l] = pv;
            }
        }
        __syncthreads();
        const int bi  = m0 >> 11;
        const int sgb = m0 & 2047;
#pragma unroll
        for (int i = 0; i < 8; ++i) {
            const int c    = i * 256 + tid;      // [0, 2048)
            const int col  = c >> 4;             // local out-col
            const int sc8  = (c & 15) * 8;       // s-chunk
            const int gcol = oc0 + col;
            const int hh   = gcol >> 6;
            const int d    = gcol & 63;
            u16* dst = vtws + (size_t)(bi * NHEADS + hh) * (SEQ * HEADDIM)
                            + (size_t)d * SEQ + sgb + sc8;
            *(bf16x8*)dst = *(const bf16x8*)&smem[col * TP + sc8];
        }
    }
}

// ---------------- kernel 2: flash attention, in-block K-split, in-register P ----------------
// grid: (SEQ/QTILE, B*H) = (32, 32). block 512 = 8 waves.
// wave w: qw = w&3 owns q rows; kg = w>>2 owns half the k range.
// Swapped QK^T: MFMA(K, Q) -> P[k=nt*16+quad*4+r][q=l16] lane-local. Softmax/bias
// applied in-register; P redistributed to the PV A-fragment layout with 3 shfl_xor
// rounds — no P LDS tile. LDS 34.3 KB.
// __launch_bounds__(512,6): VGPR cap ~85 (body needs ~70-80). Round-2's (512,8)
// capped at 64 VGPR -> massive scratch spill (FETCH 509MB/WRITE 395MB). Never
// trade required registers for occupancy.
__global__ __launch_bounds__(512, 6) void attn_kernel(
    const u16* __restrict__ qws, const u16* __restrict__ kws,
    const u16* __restrict__ vtl,
    const int* __restrict__ vids, const float* __restrict__ mask,
    const float* __restrict__ u_same, const float* __restrict__ u_cross,
    u16* __restrict__ attn)
{
    // LDS map (u16 units):
    //   [    0,  8192): K tiles   [grp][buf][32*64]
    //   [ 8192, 16384): V^T tiles [grp][buf][64*32]
    // combine phase aliases the front as float co[64][65] (16640 B).
    __shared__ alignas(16) u16 smem[16384];
    __shared__ int   bidm[2][2][KTILE];
    __shared__ float bmkm[2][2][KTILE];
    __shared__ float comb_li2[2][QTILE];

    const int bh = blockIdx.y;
    const int b  = bh >> 3;
    const int h  = bh & 7;
    const int q0 = blockIdx.x * QTILE;

    const int tid  = threadIdx.x;
    const int w    = tid >> 6;                // 0..7
    const int lane = tid & 63;
    const int quad = lane >> 4;
    const int l16  = lane & 15;
    const int qw   = w & 3;                   // q sub-tile
    const int kg   = w >> 2;                  // k group
    const int tl   = tid & 255;               // thread index within k group

    const float us2 = u_same[h]  * LOG2E;
    const float uc2 = u_cross[h] * LOG2E;
    const size_t tb = (size_t)bh * (SEQ * HEADDIM);

    const int qr = q0 + qw * 16 + l16;
    const bf16x8 aq0 = *(const bf16x8*)(qws + tb + qr * HEADDIM + quad * 8);
    const bf16x8 aq1 = *(const bf16x8*)(qws + tb + qr * HEADDIM + 32 + quad * 8);

    const int vq = vids[b * SEQ + q0 + qw * 16 + l16];   // this lane's q variate id

    float li = 0.f;
    f32x4 o[4] = {};

    // staging geometry (per k group: 256 threads stage one K + one V^T tile)
    const int srow  = tl >> 3;                // K tile row (k), 0..31
    const int scb   = tl & 7;
    const int soff  = ((scb ^ (srow & 7)) << 3);
    const int vrow  = tl >> 2;                // V^T tile row (d), 0..63
    const int vcb   = (tl & 3) ^ ((vrow >> 1) & 3);   // bank-spread swizzle
    const int soffv = (vcb << 3);
    const int kbase = kg * 2 * 2048;          // + cur*2048

    auto stage = [&](int t, int nb) {
        const int k0 = (kg * NKT_G + t) * KTILE;
        gll16(kws + tb + (size_t)(k0 + srow) * HEADDIM + soff,
              &smem[kbase + nb * 2048 + tl * 8]);
        gll16(vtl + tb + (size_t)vrow * SEQ + k0 + soffv,
              &smem[8192 + kbase + nb * 2048 + tl * 8]);
        if (tl < KTILE) {
            gll4(vids + b * SEQ + k0 + tl, &bidm[kg][nb][0]);
            gll4(mask + b * SEQ + k0 + tl, &bmkm[kg][nb][0]);
        }
    };

    auto body = [&](const int cur) {   // cur literal at call sites
        const u16* kb_b = &smem[kbase + cur * 2048];
        const u16* vb_b = &smem[8192 + kbase + cur * 2048];
        unsigned x0, x1, y0, y1;       // packed bf16 P words, nt0 (x) / nt1 (y)
#pragma unroll
        for (int nt = 0; nt < 2; ++nt) {
            const int krow = nt * 16 + l16;
            const int r7   = krow & 7;
            const bf16x8 kb0 = *(const bf16x8*)&kb_b[krow * 64 + ((quad ^ r7) << 3)];
            const bf16x8 kb1 = *(const bf16x8*)&kb_b[krow * 64 + ((quad ^ r7 ^ 4) << 3)];
            f32x4 sc = {};
            sc = MFMA(kb0, aq0, sc);   // swapped: C row = k, col = q(l16)
            sc = MFMA(kb1, aq1, sc);
            const int kk = nt * 16 + quad * 4;     // this lane's 4 k rows
            const int4   kv4 = *(const int4*)&bidm[kg][cur][kk];    // broadcast reads
            const float4 mk4 = *(const float4*)&bmkm[kg][cur][kk];
            const int   kvr[4] = { kv4.x, kv4.y, kv4.z, kv4.w };
            const float mkr[4] = { mk4.x, mk4.y, mk4.z, mk4.w };
            float p[4];
#pragma unroll
            for (int r = 0; r < 4; ++r) {
                const float mdl = fmaf(mkr[r], 1.4426950408889634e9f,
                                       -1.4426950408889634e9f - SHIFT);
                const float sel = (kvr[r] == vq) ? (us2 + mdl) : (uc2 + mdl);
                p[r] = __builtin_amdgcn_exp2f(fmaf(sc[r], SCL2, sel));
                li += p[r];
            }
            if (nt == 0) { x0 = pk_bf16(p[0], p[1]); x1 = pk_bf16(p[2], p[3]); }
            else         { y0 = pk_bf16(p[0], p[1]); y1 = pk_bf16(p[2], p[3]); }
        }

        // redistribute P to PV A-fragment layout: lane needs P[q=l16][8*quad .. 8*quad+7]
        const bool qlo = (quad < 2);
        const bool qod = (quad & 1);
        const unsigned a0 = qlo ? x0 : y0, a1 = qlo ? x1 : y1;
        const unsigned r0 = __shfl_xor((int)a0, 16), r1 = __shfl_xor((int)a1, 16);
        const unsigned b0 = qod ? x0 : y0, b1 = qod ? x1 : y1;
        const unsigned s0 = __shfl_xor((int)b0, 32), s1 = __shfl_xor((int)b1, 32);
        const unsigned c0 = qod ? y0 : x0, c1 = qod ? y1 : x1;
        const unsigned t0 = __shfl_xor((int)c0, 48), t1 = __shfl_xor((int)c1, 48);
        union { unsigned u[4]; bf16x8 v; } ap;
        ap.u[0] = (quad == 0) ? x0 : (quad == 1) ? t0 : (quad == 2) ? s0 : r0;
        ap.u[1] = (quad == 0) ? x1 : (quad == 1) ? t1 : (quad == 2) ? s1 : r1;
        ap.u[2] = (quad == 0) ? r0 : (quad == 1) ? s0 : (quad == 2) ? t0 : y0;
        ap.u[3] = (quad == 0) ? r1 : (quad == 1) ? s1 : (quad == 2) ? t1 : y1;

#pragma unroll
        for (int nt = 0; nt < 4; ++nt) {
            const int vr = nt * 16 + l16;
            const bf16x8 vb0 = *(const bf16x8*)&vb_b[vr * 32 + (((quad ^ ((vr >> 1) & 3))) << 3)];
            o[nt] = MFMA(ap.v, vb0, o[nt]);
        }
    };

    stage(0, 0);
    for (int t = 0; t < NKT_G; t += 2) {
        __syncthreads();
        stage(t + 1, 1);
        body(0);
        __syncthreads();
        if (t + 2 < NKT_G) stage(t + 2, 0);
        body(1);
    }

    // ---- combine the two k-groups' partials through LDS ----
    float liq = li + __shfl_xor(li, 16);
    liq += __shfl_xor(liq, 32);               // full kg-partial row sum, q = l16
    __syncthreads();
    float* co = (float*)smem;                 // [64][65] f32, aliases K/V buffers
    if (quad == 0) comb_li2[kg][qw * 16 + l16] = liq;
    if (kg == 1) {
#pragma unroll
        for (int nt = 0; nt < 4; ++nt)
#pragma unroll
            for (int r = 0; r < 4; ++r)
                co[(qw * 16 + quad * 4 + r) * 65 + nt * 16 + l16] = o[nt][r];
    }
    __syncthreads();
    if (kg == 0) {
#pragma unroll
        for (int r = 0; r < 4; ++r) {
            const int qloc = qw * 16 + quad * 4 + r;
            const float lt = comb_li2[0][qloc] + comb_li2[1][qloc];
            const float inv = 1.0f / lt;
            const int R  = q0 + qloc;
            const int rb = (b * SEQ + R) * DMODEL + h * HEADDIM;
#pragma unroll
            for (int nt = 0; nt < 4; ++nt)
                attn[rb + nt * 16 + l16] =
                    f2bf((o[nt][r] + co[qloc * 65 + nt * 16 + l16]) * inv);
        }
    }
}

// ---------------- kernel 3: output projection (swapped A/B, LDS store, fp32 out) ----------------
__global__ __launch_bounds__(256) void proj_kernel(
    const u16* __restrict__ a, const u16* __restrict__ Wo,
    const float* __restrict__ bo, float* __restrict__ out)
{
    __shared__ alignas(16) u16 psm[132 * 64 * 2];    // 33792 B; As/Bs alias front, Lp aliases all
    u16* As = psm;
    u16* Bs = psm + 8192;
    float* Lp = (float*)psm;                         // 64 x 132 f32 tile

    const int m0 = blockIdx.x * 128;                 // attn-row tile
    const int n0 = blockIdx.y * 128;                 // out-col strip
    const int tid  = threadIdx.x;
    const int w    = tid >> 6;
    const int lane = tid & 63;
    const int quad = lane >> 4;
    const int l16  = lane & 15;
    const int wm = w & 1, wn = w >> 1;               // wm: W-col tile, wn: s tile

    f32x4 acc[4][4] = {};

    for (int kb = 0; kb < 8; ++kb) {
#pragma unroll
        for (int it = 0; it < 4; ++it) {
            const int s   = it * 256 + tid;
            const int row = s >> 3;
            const int cb  = s & 7;
            const int gcol = kb * 64 + (((cb ^ (row & 7))) << 3);
            gll16(a  + (m0 + row) * 512 + gcol, &As[s * 8]);
            gll16(Wo + (n0 + row) * 512 + gcol, &Bs[s * 8]);
        }
        __syncthreads();

#pragma unroll
        for (int ks = 0; ks < 2; ++ks) {
            bf16x8 af[4], wf[4];
#pragma unroll
            for (int t = 0; t < 4; ++t) {
                const int arow = wn * 64 + t * 16 + l16;
                const int wrow = wm * 64 + t * 16 + l16;
                af[t] = *(const bf16x8*)&As[arow * 64 + (((ks * 4 + quad) ^ (arow & 7)) << 3)];
                wf[t] = *(const bf16x8*)&Bs[wrow * 64 + (((ks * 4 + quad) ^ (wrow & 7)) << 3)];
            }
#pragma unroll
            for (int tm = 0; tm < 4; ++tm)
#pragma unroll
                for (int tn = 0; tn < 4; ++tn)
                    acc[tm][tn] = MFMA(wf[tm], af[tn], acc[tm][tn]);  // C row=d, col=s
        }
        __syncthreads();
    }

    // two phases by s-half: waves wn==hph write Lp[s2][d], all threads store coalesced
#pragma unroll
    for (int hph = 0; hph < 2; ++hph) {
        if (wn == hph) {
#pragma unroll
            for (int tm = 0; tm < 4; ++tm) {
                const int dls = wm * 64 + tm * 16 + quad * 4;
                const float4 bv4 = *(const float4*)&bo[n0 + dls];
#pragma unroll
                for (int tn = 0; tn < 4; ++tn) {
                    const int s2 = tn * 16 + l16;            // [0,64)
                    float4 v = { acc[tm][tn][0] + bv4.x, acc[tm][tn][1] + bv4.y,
                                 acc[tm][tn][2] + bv4.z, acc[tm][tn][3] + bv4.w };
                    *(float4*)&Lp[s2 * 132 + dls] = v;
                }
            }
        }
        __syncthreads();
#pragma unroll
        for (int i = 0; i < 8; ++i) {
            const int c  = i * 256 + tid;        // [0,2048)
            const int s2 = c >> 5;               // [0,64)
            const int dq = (c & 31) * 4;         // [0,128)
            float4 v = *(const float4*)&Lp[s2 * 132 + dq];
            *(float4*)&out[(size_t)(m0 + hph * 64 + s2) * 512 + n0 + dq] = v;
        }
        __syncthreads();
    }
}

// ---------------- launch ----------------
extern "C" void kernel_launch(void* const* d_in, const int* in_sizes, int n_in,
                              void* d_out, int out_size, void* d_ws, size_t ws_size,
                              hipStream_t stream) {
    const float* x    = (const float*)d_in[0];
    const int*   vids = (const int*)d_in[1];
    const float* mask = (const float*)d_in[2];
    const float* Wq = (const float*)d_in[3];
    const float* bq = (const float*)d_in[4];
    const float* Wk = (const float*)d_in[5];
    const float* bk = (const float*)d_in[6];
    const float* Wv = (const float*)d_in[7];
    const float* bv = (const float*)d_in[8];
    const float* Wo = (const float*)d_in[9];
    const float* bo = (const float*)d_in[10];
    const float* usame  = (const float*)d_in[11];
    const float* ucross = (const float*)d_in[12];
    float* out = (float*)d_out;

    u16* xbf  = (u16*)d_ws;                 // 8 MB; reused as attention output
    u16* wqbf = xbf + NX;                   // 512 KB each
    u16* wkbf = wqbf + NW;
    u16* wvbf = wkbf + NW;
    u16* wobf = wvbf + NW;
    float2* cst = (float2*)(wobf + NW);     // 512 KB
    u16* qws  = (u16*)(cst + SEQ * 32);     // 8 MB each
    u16* kws  = qws + (size_t)BATCH * NHEADS * SEQ * HEADDIM;
    u16* vtws = kws + (size_t)BATCH * NHEADS * SEQ * HEADDIM;
    u16* attn = xbf;

    cvt_rope_kernel<<<(NCVT4 + SEQ * 32 / 4 + 255) / 256, 256, 0, stream>>>(
        x, Wq, Wk, Wv, Wo, xbf, wqbf, wkbf, wvbf, wobf, cst);

    dim3 g1(MTOT / 128, 3 * DMODEL / 128);  // 64 x 12
    qkv_kernel<<<g1, 256, 0, stream>>>(xbf, wqbf, bq, wkbf, bk, wvbf, bv,
                                       (const float*)cst, qws, kws, vtws);

    dim3 g2(SEQ / QTILE, BATCH * NHEADS);   // 32 x 32
    attn_kernel<<<g2, 512, 0, stream>>>(qws, kws, vtws, vids, mask,
                                        usame, ucross, attn);

    dim3 g3(MTOT / 128, DMODEL / 128);      // 64 x 4
    proj_kernel<<<g3, 256, 0, stream>>>(attn, wobf, bo, out);
}

// Round 5
// 194.024 us; speedup vs baseline: 1.7358x; 1.0693x over previous
//
#include <hip/hip_runtime.h>
#include <hip/hip_bf16.h>

// ---------------- problem constants ----------------
#define BATCH   4
#define SEQ     2048
#define DMODEL  512
#define NHEADS  8
#define HEADDIM 64
#define MTOT    (BATCH*SEQ)      // 8192 rows
#define NX      (MTOT*DMODEL)    // 4194304 x elements
#define NW      (DMODEL*DMODEL)  // 262144 weight elements
#define QTILE   64               // q rows per block (4 q-waves x 16)
#define KTILE   32               // k rows per tile
#define NKT_G   32               // tiles per k-group (2 groups cover SEQ)

#define LOG2E   1.4426950408889634f
#define SCL2    0.18033688011112042f      // 0.125 * log2e
#define SHIFT   14.426950408889634f       // overflow headroom shift
#define BIGL    1.4426950408889634e9f     // 1e9 * log2e
// ---------------------------------------------------

typedef unsigned short u16;
typedef __bf16 bf16x8 __attribute__((ext_vector_type(8)));
typedef float  f32x4  __attribute__((ext_vector_type(4)));
typedef unsigned short u16x4 __attribute__((ext_vector_type(4)));
typedef unsigned u32x2 __attribute__((ext_vector_type(2)));

#define MFMA(a,b,c) __builtin_amdgcn_mfma_f32_16x16x32_bf16(a,b,c,0,0,0)

__device__ __forceinline__ u16 f2bf(float f) {
    unsigned u = __float_as_uint(f);
    u += 0x7FFFu + ((u >> 16) & 1u);   // RNE
    return (u16)(u >> 16);
}
__device__ __forceinline__ unsigned pk_bf16(float a, float b) {
    union { __hip_bfloat162 h; unsigned u; } cv;
    cv.h = __float22bfloat162_rn(make_float2(a, b));
    return cv.u;
}
__device__ __forceinline__ void gll16(const void* g, void* l) {
    __builtin_amdgcn_global_load_lds((const __attribute__((address_space(1))) void*)g,
                                     (__attribute__((address_space(3))) void*)l, 16, 0, 0);
}
__device__ __forceinline__ void gll4(const void* g, void* l) {
    __builtin_amdgcn_global_load_lds((const __attribute__((address_space(1))) void*)g,
                                     (__attribute__((address_space(3))) void*)l, 4, 0, 0);
}

// ---------------- kernel 0: fp32 -> bf16 converts + rope cos/sin table ----------------
#define NCVT4 ((NX + 4*NW)/4)    // 1310720 float4 groups
__global__ __launch_bounds__(256) void cvt_rope_kernel(
    const float* __restrict__ x,
    const float* __restrict__ wq, const float* __restrict__ wk,
    const float* __restrict__ wv, const float* __restrict__ wo,
    u16* __restrict__ xbf,
    u16* __restrict__ wqbf, u16* __restrict__ wkbf,
    u16* __restrict__ wvbf, u16* __restrict__ wobf,
    float2* __restrict__ cst)
{
    int i4 = blockIdx.x * 256 + threadIdx.x;
    if (i4 < NCVT4) {
        int i = i4 * 4;
        const float* s; u16* d; int o;
        if (i < NX) { s = x; d = xbf; o = i; }
        else {
            int j = i - NX;
            int r = j >> 18;            // NW = 2^18
            o = j & (NW - 1);
            s = (r == 0) ? wq : (r == 1) ? wk : (r == 2) ? wv : wo;
            d = (r == 0) ? wqbf : (r == 1) ? wkbf : (r == 2) ? wvbf : wobf;
        }
        float4 v = *(const float4*)(s + o);
        u16x4 u = { f2bf(v.x), f2bf(v.y), f2bf(v.z), f2bf(v.w) };
        *(u16x4*)(d + o) = u;
    } else {
        int r = i4 - NCVT4;             // [0, 16384)
        if (r < SEQ * 32 / 4) {
            int idx = r * 4;
            int s  = idx >> 5;
            int p0 = idx & 31;
#pragma unroll
            for (int t = 0; t < 4; ++t) {
                int p = p0 + t;
                float inv = __expf(-0.5756462732485115f * (float)(p & 15));
                float ang = (float)s * inv;
                cst[idx + t] = make_float2(cosf(ang), sinf(ang));
            }
        }
    }
}

// ---------------- kernel 1: fused QKV projection + RoPE (128x128, LDS-staged) ----------------
#define TP 136   // LDS tile row stride (u16 elems)
__global__ __launch_bounds__(256) void qkv_kernel(
    const u16* __restrict__ x,
    const u16* __restrict__ Wq, const float* __restrict__ bq,
    const u16* __restrict__ Wk, const float* __restrict__ bk,
    const u16* __restrict__ Wv, const float* __restrict__ bv,
    const float* __restrict__ cstf,     // cst as float*, {cos,sin} interleaved
    u16* __restrict__ qws, u16* __restrict__ kws, u16* __restrict__ vtws)
{
    __shared__ alignas(16) u16 smem[128 * TP];   // 34816 B; As/Bs alias the front
    u16* As = smem;            // x tile   128x64
    u16* Bs = smem + 8192;     // W tile   128x64

    const int m0 = blockIdx.x * 128;         // x-row tile
    const int n0 = blockIdx.y * 128;         // col tile over 1536
    const int tid  = threadIdx.x;
    const int w    = tid >> 6;
    const int lane = tid & 63;
    const int quad = lane >> 4;
    const int l16  = lane & 15;
    const int wm = w & 1, wn = w >> 1;

    const int sec = n0 >> 9;                 // 0=Q 1=K 2=V
    const int oc0 = n0 & 511;
    const u16*   Wm = (sec == 0) ? Wq : (sec == 1 ? Wk : Wv);
    const float* bb = (sec == 0) ? bq : (sec == 1 ? bk : bv);

    const int xb = (sec < 2) ? wn : wm;      // x-row fragment base
    const int wb = (sec < 2) ? wm : wn;      // W-row fragment base

    f32x4 acc[4][4] = {};

    for (int kb = 0; kb < 8; ++kb) {
#pragma unroll
        for (int it = 0; it < 4; ++it) {
            const int s   = it * 256 + tid;
            const int row = s >> 3;
            const int cb  = s & 7;
            const int gcol = kb * 64 + (((cb ^ (row & 7))) << 3);
            gll16(x  + (m0  + row) * 512 + gcol, &As[s * 8]);
            gll16(Wm + (oc0 + row) * 512 + gcol, &Bs[s * 8]);
        }
        __syncthreads();

#pragma unroll
        for (int ks = 0; ks < 2; ++ks) {
            bf16x8 xf[4], wf[4];
#pragma unroll
            for (int t = 0; t < 4; ++t) {
                const int xrow = xb * 64 + t * 16 + l16;
                const int wrow = wb * 64 + t * 16 + l16;
                xf[t] = *(const bf16x8*)&As[xrow * 64 + (((ks * 4 + quad) ^ (xrow & 7)) << 3)];
                wf[t] = *(const bf16x8*)&Bs[wrow * 64 + (((ks * 4 + quad) ^ (wrow & 7)) << 3)];
            }
            if (sec < 2) {
#pragma unroll
                for (int tm = 0; tm < 4; ++tm)
#pragma unroll
                    for (int tn = 0; tn < 4; ++tn)
                        acc[tm][tn] = MFMA(wf[tm], xf[tn], acc[tm][tn]);  // C row=d, col=s
            } else {
#pragma unroll
                for (int tm = 0; tm < 4; ++tm)
#pragma unroll
                    for (int tn = 0; tn < 4; ++tn)
                        acc[tm][tn] = MFMA(xf[tm], wf[tn], acc[tm][tn]);  // C row=s, col=d
            }
        }
        __syncthreads();
    }

    if (sec < 2) {
        // ---- Q/K epilogue: C row = head-dim, col = s. rope fully in-register ----
#pragma unroll
        for (int tm = 0; tm < 4; ++tm) {
            const int dls = wm * 64 + tm * 16 + quad * 4;         // local d base (mult of 4)
            const float4 bv4 = *(const float4*)&bb[oc0 + dls];
            const int pbase = ((oc0 + dls) & 63) >> 1;            // rope pair idx (even)
#pragma unroll
            for (int tn = 0; tn < 4; ++tn) {
                const int sl = wn * 64 + tn * 16 + l16;           // local s
                const int sg = (m0 + sl) & 2047;                  // seq pos
                const float4 cs = *(const float4*)&cstf[sg * 64 + pbase * 2]; // c0,s0,c1,s1
                const float v0 = acc[tm][tn][0] + bv4.x;
                const float v1 = acc[tm][tn][1] + bv4.y;
                const float v2 = acc[tm][tn][2] + bv4.z;
                const float v3 = acc[tm][tn][3] + bv4.w;
                const float r0 = v0 * cs.x - v1 * cs.y;
                const float r1 = v1 * cs.x + v0 * cs.y;
                const float r2 = v2 * cs.z - v3 * cs.w;
                const float r3 = v3 * cs.z + v2 * cs.w;
                u32x2 pv = { pk_bf16(r0, r1), pk_bf16(r2, r3) };
                *(u32x2*)&smem[sl * TP + dls] = pv;
            }
        }
        __syncthreads();
        u16* dst0 = (sec == 0) ? qws : kws;
#pragma unroll
        for (int i = 0; i < 8; ++i) {
            const int c   = i * 256 + tid;       // [0, 2048)
            const int sl  = c >> 4;              // local s row
            const int d8  = (c & 15) * 8;        // 8-dim chunk
            const int gcol = oc0 + d8;
            const int hh  = gcol >> 6;
            const int dh  = gcol & 63;
            const int sgl = m0 + sl;
            const int bi  = sgl >> 11;
            const int s   = sgl & 2047;
            u16* dst = dst0 + (size_t)(bi * NHEADS + hh) * (SEQ * HEADDIM)
                            + (size_t)s * HEADDIM + dh;
            *(bf16x8*)dst = *(const bf16x8*)&smem[sl * TP + d8];
        }
    } else {
        // ---- V epilogue: C row = s, col = out-col d. LDS transpose T[d][s] ----
#pragma unroll
        for (int tm = 0; tm < 4; ++tm) {
            const int row_l = wm * 64 + tm * 16 + quad * 4;      // local s rows
#pragma unroll
            for (int tn = 0; tn < 4; ++tn) {
                const int col_l = wn * 64 + tn * 16 + l16;       // local out-col
                const float bval = bb[oc0 + col_l];
                u32x2 pv = { pk_bf16(acc[tm][tn][0] + bval, acc[tm][tn][1] + bval),
                             pk_bf16(acc[tm][tn][2] + bval, acc[tm][tn][3] + bval) };
                *(u32x2*)&smem[col_l * TP + row_l] = pv;
            }
        }
        __syncthreads();
        const int bi  = m0 >> 11;
        const int sgb = m0 & 2047;
#pragma unroll
        for (int i = 0; i < 8; ++i) {
            const int c    = i * 256 + tid;      // [0, 2048)
            const int col  = c >> 4;             // local out-col
            const int sc8  = (c & 15) * 8;       // s-chunk
            const int gcol = oc0 + col;
            const int hh   = gcol >> 6;
            const int d    = gcol & 63;
            u16* dst = vtws + (size_t)(bi * NHEADS + hh) * (SEQ * HEADDIM)
                            + (size_t)d * SEQ + sgb + sc8;
            *(bf16x8*)dst = *(const bf16x8*)&smem[col * TP + sc8];
        }
    }
}

// ---------------- kernel 2: flash attention, in-block K-split, LDS-P v2 ----------------
// grid: (SEQ/QTILE, B*H) = (32, 32), XCD-swizzled: all 32 q-tiles of a (b,h)
// land on the same XCD (id%8 = const) so K/V stay resident in that XCD's L2,
// cutting the staging latency the per-iteration barrier exposes.
// block 512 = 8 waves; qw = w&3 owns q rows, kg = w>>2 owns half the k range.
// Swapped QK^T: MFMA(K, Q) -> P[k][q=l16] lane-local; P bounced through a
// per-wave LDS tile [16][40] (2-way max aliasing): one u32x2 store per nt
// + one ds_read_b128 gives the PV A-frag. No barrier (wave-private tile).
// (Round-3's shfl transpose = 6 ds_bpermute + 14 cndmask was slower.)
// __launch_bounds__(512,6): VGPR cap ~85; (512,8) caused catastrophic spill.
__global__ __launch_bounds__(512, 6) void attn_kernel(
    const u16* __restrict__ qws, const u16* __restrict__ kws,
    const u16* __restrict__ vtl,
    const int* __restrict__ vids, const float* __restrict__ mask,
    const float* __restrict__ u_same, const float* __restrict__ u_cross,
    u16* __restrict__ attn)
{
    // LDS map (u16 units):
    //   [    0,  8192): K tiles   [grp][buf][32*64]
    //   [ 8192, 16384): V^T tiles [grp][buf][64*32]
    // combine phase aliases the front as float co[64][65] (16640 B).
    __shared__ alignas(16) u16 smem[16384];
    __shared__ alignas(16) u16 plsm[8 * 16 * 40];   // per-wave P tiles [16][40]
    __shared__ int   bidm[2][2][KTILE];
    __shared__ float bmkm[2][2][KTILE];
    __shared__ float comb_li2[2][QTILE];

    // XCD-locality swizzle (bijective; perf-neutral if dispatch mapping differs)
    const int id  = blockIdx.y * 32 + blockIdx.x;
    const int xcd = id & 7;
    const int idx = id >> 3;                  // [0,128)
    const int bh  = xcd * 4 + (idx & 3);
    const int q0  = (idx >> 2) * QTILE;
    const int b   = bh >> 3;
    const int h   = bh & 7;

    const int tid  = threadIdx.x;
    const int w    = tid >> 6;                // 0..7
    const int lane = tid & 63;
    const int quad = lane >> 4;
    const int l16  = lane & 15;
    const int qw   = w & 3;                   // q sub-tile
    const int kg   = w >> 2;                  // k group
    const int tl   = tid & 255;               // thread index within k group

    const float us2 = u_same[h]  * LOG2E;
    const float uc2 = u_cross[h] * LOG2E;
    const float uc3 = uc2 - BIGL - SHIFT;     // folded constant
    const float du2 = us2 - uc2;              // same-vs-cross delta
    const size_t tb = (size_t)bh * (SEQ * HEADDIM);

    const int qr = q0 + qw * 16 + l16;
    const bf16x8 aq0 = *(const bf16x8*)(qws + tb + qr * HEADDIM + quad * 8);
    const bf16x8 aq1 = *(const bf16x8*)(qws + tb + qr * HEADDIM + 32 + quad * 8);

    const int vq = vids[b * SEQ + q0 + qw * 16 + l16];   // this lane's q variate id

    float li = 0.f;
    f32x4 o[4] = {};

    // staging geometry (per k group: 256 threads stage one K + one V^T tile)
    const int srow  = tl >> 3;                // K tile row (k), 0..31
    const int scb   = tl & 7;
    const int soff  = ((scb ^ (srow & 7)) << 3);
    const int vrow  = tl >> 2;                // V^T tile row (d), 0..63
    const int vcb   = (tl & 3) ^ ((vrow >> 1) & 3);   // bank-spread swizzle
    const int soffv = (vcb << 3);
    const int kbase = kg * 2 * 2048;          // + cur*2048

    auto stage = [&](int t, int nb) {
        const int k0 = (kg * NKT_G + t) * KTILE;
        gll16(kws + tb + (size_t)(k0 + srow) * HEADDIM + soff,
              &smem[kbase + nb * 2048 + tl * 8]);
        gll16(vtl + tb + (size_t)vrow * SEQ + k0 + soffv,
              &smem[8192 + kbase + nb * 2048 + tl * 8]);
        if (tl < KTILE) {
            gll4(vids + b * SEQ + k0 + tl, &bidm[kg][nb][0]);
            gll4(mask + b * SEQ + k0 + tl, &bmkm[kg][nb][0]);
        }
    };

    u16* const pw = &plsm[w * 640];           // this wave's P tile [16][40]

    auto body = [&](const int cur) {   // cur literal at call sites
        const u16* kb_b = &smem[kbase + cur * 2048];
        const u16* vb_b = &smem[8192 + kbase + cur * 2048];
#pragma unroll
        for (int nt = 0; nt < 2; ++nt) {
            const int krow = nt * 16 + l16;
            const int r7   = krow & 7;
            const bf16x8 kb0 = *(const bf16x8*)&kb_b[krow * 64 + ((quad ^ r7) << 3)];
            const bf16x8 kb1 = *(const bf16x8*)&kb_b[krow * 64 + ((quad ^ r7 ^ 4) << 3)];
            f32x4 sc = {};
            sc = MFMA(kb0, aq0, sc);   // swapped: C row = k, col = q(l16)
            sc = MFMA(kb1, aq1, sc);
            const int kk = nt * 16 + quad * 4;     // this lane's 4 k rows
            const int4   kv4 = *(const int4*)&bidm[kg][cur][kk];    // broadcast reads
            const float4 mk4 = *(const float4*)&bmkm[kg][cur][kk];
            const int   kvr[4] = { kv4.x, kv4.y, kv4.z, kv4.w };
            const float mkr[4] = { mk4.x, mk4.y, mk4.z, mk4.w };
            float p[4];
#pragma unroll
            for (int r = 0; r < 4; ++r) {
                const float sel = fmaf(mkr[r], BIGL, uc3) + ((kvr[r] == vq) ? du2 : 0.0f);
                p[r] = __builtin_amdgcn_exp2f(fmaf(sc[r], SCL2, sel));
                li += p[r];
            }
            // P[q=l16][k=nt*16+quad*4 .. +3] as 2 packed words -> one 8B store
            u32x2 pv = { pk_bf16(p[0], p[1]), pk_bf16(p[2], p[3]) };
            *(u32x2*)&pw[l16 * 40 + nt * 16 + quad * 4] = pv;
        }

        // PV A-frag: P[q=l16][quad*8 .. quad*8+7], one b128 read (wave-private)
        const bf16x8 ap = *(const bf16x8*)&pw[l16 * 40 + quad * 8];

#pragma unroll
        for (int nt = 0; nt < 4; ++nt) {
            const int vr = nt * 16 + l16;
            const bf16x8 vb0 = *(const bf16x8*)&vb_b[vr * 32 + (((quad ^ ((vr >> 1) & 3))) << 3)];
            o[nt] = MFMA(ap, vb0, o[nt]);
        }
    };

    stage(0, 0);
    for (int t = 0; t < NKT_G; t += 2) {
        __syncthreads();
        stage(t + 1, 1);
        body(0);
        __syncthreads();
        if (t + 2 < NKT_G) stage(t + 2, 0);
        body(1);
    }

    // ---- combine the two k-groups' partials through LDS ----
    float liq = li + __shfl_xor(li, 16);
    liq += __shfl_xor(liq, 32);               // full kg-partial row sum, q = l16
    __syncthreads();
    float* co = (float*)smem;                 // [64][65] f32, aliases K/V buffers
    if (quad == 0) comb_li2[kg][qw * 16 + l16] = liq;
    if (kg == 1) {
#pragma unroll
        for (int nt = 0; nt < 4; ++nt)
#pragma unroll
            for (int r = 0; r < 4; ++r)
                co[(qw * 16 + quad * 4 + r) * 65 + nt * 16 + l16] = o[nt][r];
    }
    __syncthreads();
    if (kg == 0) {
#pragma unroll
        for (int r = 0; r < 4; ++r) {
            const int qloc = qw * 16 + quad * 4 + r;
            const float lt = comb_li2[0][qloc] + comb_li2[1][qloc];
            const float inv = 1.0f / lt;
            const int R  = q0 + qloc;
            const int rb = (b * SEQ + R) * DMODEL + h * HEADDIM;
#pragma unroll
            for (int nt = 0; nt < 4; ++nt)
                attn[rb + nt * 16 + l16] =
                    f2bf((o[nt][r] + co[qloc * 65 + nt * 16 + l16]) * inv);
        }
    }
}

// ---------------- kernel 3: output projection (swapped A/B, LDS store, fp32 out) ----------------
__global__ __launch_bounds__(256) void proj_kernel(
    const u16* __restrict__ a, const u16* __restrict__ Wo,
    const float* __restrict__ bo, float* __restrict__ out)
{
    __shared__ alignas(16) u16 psm[132 * 64 * 2];    // 33792 B; As/Bs alias front, Lp aliases all
    u16* As = psm;
    u16* Bs = psm + 8192;
    float* Lp = (float*)psm;                         // 64 x 132 f32 tile

    const int m0 = blockIdx.x * 128;                 // attn-row tile
    const int n0 = blockIdx.y * 128;                 // out-col strip
    const int tid  = threadIdx.x;
    const int w    = tid >> 6;
    const int lane = tid & 63;
    const int quad = lane >> 4;
    const int l16  = lane & 15;
    const int wm = w & 1, wn = w >> 1;               // wm: W-col tile, wn: s tile

    f32x4 acc[4][4] = {};

    for (int kb = 0; kb < 8; ++kb) {
#pragma unroll
        for (int it = 0; it < 4; ++it) {
            const int s   = it * 256 + tid;
            const int row = s >> 3;
            const int cb  = s & 7;
            const int gcol = kb * 64 + (((cb ^ (row & 7))) << 3);
            gll16(a  + (m0 + row) * 512 + gcol, &As[s * 8]);
            gll16(Wo + (n0 + row) * 512 + gcol, &Bs[s * 8]);
        }
        __syncthreads();

#pragma unroll
        for (int ks = 0; ks < 2; ++ks) {
            bf16x8 af[4], wf[4];
#pragma unroll
            for (int t = 0; t < 4; ++t) {
                const int arow = wn * 64 + t * 16 + l16;
                const int wrow = wm * 64 + t * 16 + l16;
                af[t] = *(const bf16x8*)&As[arow * 64 + (((ks * 4 + quad) ^ (arow & 7)) << 3)];
                wf[t] = *(const bf16x8*)&Bs[wrow * 64 + (((ks * 4 + quad) ^ (wrow & 7)) << 3)];
            }
#pragma unroll
            for (int tm = 0; tm < 4; ++tm)
#pragma unroll
                for (int tn = 0; tn < 4; ++tn)
                    acc[tm][tn] = MFMA(wf[tm], af[tn], acc[tm][tn]);  // C row=d, col=s
        }
        __syncthreads();
    }

    // two phases by s-half: waves wn==hph write Lp[s2][d], all threads store coalesced
#pragma unroll
    for (int hph = 0; hph < 2; ++hph) {
        if (wn == hph) {
#pragma unroll
            for (int tm = 0; tm < 4; ++tm) {
                const int dls = wm * 64 + tm * 16 + quad * 4;
                const float4 bv4 = *(const float4*)&bo[n0 + dls];
#pragma unroll
                for (int tn = 0; tn < 4; ++tn) {
                    const int s2 = tn * 16 + l16;            // [0,64)
                    float4 v = { acc[tm][tn][0] + bv4.x, acc[tm][tn][1] + bv4.y,
                                 acc[tm][tn][2] + bv4.z, acc[tm][tn][3] + bv4.w };
                    *(float4*)&Lp[s2 * 132 + dls] = v;
                }
            }
        }
        __syncthreads();
#pragma unroll
        for (int i = 0; i < 8; ++i) {
            const int c  = i * 256 + tid;        // [0,2048)
            const int s2 = c >> 5;               // [0,64)
            const int dq = (c & 31) * 4;         // [0,128)
            float4 v = *(const float4*)&Lp[s2 * 132 + dq];
            *(float4*)&out[(size_t)(m0 + hph * 64 + s2) * 512 + n0 + dq] = v;
        }
        __syncthreads();
    }
}

// ---------------- launch ----------------
extern "C" void kernel_launch(void* const* d_in, const int* in_sizes, int n_in,
                              void* d_out, int out_size, void* d_ws, size_t ws_size,
                              hipStream_t stream) {
    const float* x    = (const float*)d_in[0];
    const int*   vids = (const int*)d_in[1];
    const float* mask = (const float*)d_in[2];
    const float* Wq = (const float*)d_in[3];
    const float* bq = (const float*)d_in[4];
    const float* Wk = (const float*)d_in[5];
    const float* bk = (const float*)d_in[6];
    const float* Wv = (const float*)d_in[7];
    const float* bv = (const float*)d_in[8];
    const float* Wo = (const float*)d_in[9];
    const float* bo = (const float*)d_in[10];
    const float* usame  = (const float*)d_in[11];
    const float* ucross = (const float*)d_in[12];
    float* out = (float*)d_out;

    u16* xbf  = (u16*)d_ws;                 // 8 MB; reused as attention output
    u16* wqbf = xbf + NX;                   // 512 KB each
    u16* wkbf = wqbf + NW;
    u16* wvbf = wkbf + NW;
    u16* wobf = wvbf + NW;
    float2* cst = (float2*)(wobf + NW);     // 512 KB
    u16* qws  = (u16*)(cst + SEQ * 32);     // 8 MB each
    u16* kws  = qws + (size_t)BATCH * NHEADS * SEQ * HEADDIM;
    u16* vtws = kws + (size_t)BATCH * NHEADS * SEQ * HEADDIM;
    u16* attn = xbf;

    cvt_rope_kernel<<<(NCVT4 + SEQ * 32 / 4 + 255) / 256, 256, 0, stream>>>(
        x, Wq, Wk, Wv, Wo, xbf, wqbf, wkbf, wvbf, wobf, cst);

    dim3 g1(MTOT / 128, 3 * DMODEL / 128);  // 64 x 12
    qkv_kernel<<<g1, 256, 0, stream>>>(xbf, wqbf, bq, wkbf, bk, wvbf, bv,
                                       (const float*)cst, qws, kws, vtws);

    dim3 g2(SEQ / QTILE, BATCH * NHEADS);   // 32 x 32
    attn_kernel<<<g2, 512, 0, stream>>>(qws, kws, vtws, vids, mask,
                                        usame, ucross, attn);

    dim3 g3(MTOT / 128, DMODEL / 128);      // 64 x 4
    proj_kernel<<<g3, 256, 0, stream>>>(attn, wobf, bo, out);
}

// Round 8
// 190.422 us; speedup vs baseline: 1.7686x; 1.0189x over previous
//
#include <hip/hip_runtime.h>
#include <hip/hip_bf16.h>

// ---------------- problem constants ----------------
#define BATCH   4
#define SEQ     2048
#define DMODEL  512
#define NHEADS  8
#define HEADDIM 64
#define MTOT    (BATCH*SEQ)      // 8192 rows
#define NX      (MTOT*DMODEL)    // 4194304 x elements
#define NW      (DMODEL*DMODEL)  // 262144 weight elements
#define QTILE   64               // q rows per block (4 q-waves x 16)
#define KTILE   32               // k rows per tile
#define NKT_G   32               // tiles per k-group (2 groups cover SEQ)

#define LOG2E   1.4426950408889634f
#define SCL2    0.18033688011112042f      // 0.125 * log2e
#define SHIFT   14.426950408889634f       // overflow headroom shift
#define BIGL    1.4426950408889634e9f     // 1e9 * log2e
// ---------------------------------------------------

#if __has_builtin(__builtin_amdgcn_permlane32_swap) && __has_builtin(__builtin_amdgcn_permlane16_swap)
#define HAS_PERMLANE 1
#else
#define HAS_PERMLANE 0
#endif

typedef unsigned short u16;
typedef __bf16 bf16x8 __attribute__((ext_vector_type(8)));
typedef float  f32x4  __attribute__((ext_vector_type(4)));
typedef unsigned short u16x4 __attribute__((ext_vector_type(4)));
typedef unsigned u32x2 __attribute__((ext_vector_type(2)));

#define MFMA(a,b,c) __builtin_amdgcn_mfma_f32_16x16x32_bf16(a,b,c,0,0,0)

__device__ __forceinline__ u16 f2bf(float f) {
    unsigned u = __float_as_uint(f);
    u += 0x7FFFu + ((u >> 16) & 1u);   // RNE
    return (u16)(u >> 16);
}
__device__ __forceinline__ unsigned pk_bf16(float a, float b) {
    union { __hip_bfloat162 h; unsigned u; } cv;
    cv.h = __float22bfloat162_rn(make_float2(a, b));
    return cv.u;
}
__device__ __forceinline__ void gll16(const void* g, void* l) {
    __builtin_amdgcn_global_load_lds((const __attribute__((address_space(1))) void*)g,
                                     (__attribute__((address_space(3))) void*)l, 16, 0, 0);
}
__device__ __forceinline__ void gll4(const void* g, void* l) {
    __builtin_amdgcn_global_load_lds((const __attribute__((address_space(1))) void*)g,
                                     (__attribute__((address_space(3))) void*)l, 4, 0, 0);
}

// ---------------- kernel 0: fp32 -> bf16 converts + rope table + mask bias ----------------
#define NCVT4 ((NX + 4*NW)/4)    // 1310720 float4 groups
#define NCST4 (SEQ * 32 / 4)     // 16384 cst slots
#define NMSK4 (BATCH * SEQ / 4)  // 2048 mask-bias slots
__global__ __launch_bounds__(256) void cvt_rope_kernel(
    const float* __restrict__ x,
    const float* __restrict__ wq, const float* __restrict__ wk,
    const float* __restrict__ wv, const float* __restrict__ wo,
    const float* __restrict__ mask,
    u16* __restrict__ xbf,
    u16* __restrict__ wqbf, u16* __restrict__ wkbf,
    u16* __restrict__ wvbf, u16* __restrict__ wobf,
    float2* __restrict__ cst, float* __restrict__ Mws)
{
    int i4 = blockIdx.x * 256 + threadIdx.x;
    if (i4 < NCVT4) {
        int i = i4 * 4;
        const float* s; u16* d; int o;
        if (i < NX) { s = x; d = xbf; o = i; }
        else {
            int j = i - NX;
            int r = j >> 18;            // NW = 2^18
            o = j & (NW - 1);
            s = (r == 0) ? wq : (r == 1) ? wk : (r == 2) ? wv : wo;
            d = (r == 0) ? wqbf : (r == 1) ? wkbf : (r == 2) ? wvbf : wobf;
        }
        float4 v = *(const float4*)(s + o);
        u16x4 u = { f2bf(v.x), f2bf(v.y), f2bf(v.z), f2bf(v.w) };
        *(u16x4*)(d + o) = u;
    } else {
        int r = i4 - NCVT4;
        if (r < NCST4) {                // rope cos/sin table
            int idx = r * 4;
            int s  = idx >> 5;
            int p0 = idx & 31;
#pragma unroll
            for (int t = 0; t < 4; ++t) {
                int p = p0 + t;
                float inv = __expf(-0.5756462732485115f * (float)(p & 15));
                float ang = (float)s * inv;
                cst[idx + t] = make_float2(cosf(ang), sinf(ang));
            }
        } else if (r < NCST4 + NMSK4) { // mask bias: M = (mask-1)*BIGL - SHIFT
            int idx = (r - NCST4) * 4;
            float4 mv = *(const float4*)&mask[idx];
            float4 ov = { fmaf(mv.x - 1.0f, BIGL, -SHIFT), fmaf(mv.y - 1.0f, BIGL, -SHIFT),
                          fmaf(mv.z - 1.0f, BIGL, -SHIFT), fmaf(mv.w - 1.0f, BIGL, -SHIFT) };
            *(float4*)&Mws[idx] = ov;
        }
    }
}

// ---------------- kernel 1: fused QKV projection + RoPE (128x128, LDS-staged) ----------------
#define TP 136   // LDS tile row stride (u16 elems)
__global__ __launch_bounds__(256) void qkv_kernel(
    const u16* __restrict__ x,
    const u16* __restrict__ Wq, const float* __restrict__ bq,
    const u16* __restrict__ Wk, const float* __restrict__ bk,
    const u16* __restrict__ Wv, const float* __restrict__ bv,
    const float* __restrict__ cstf,     // cst as float*, {cos,sin} interleaved
    u16* __restrict__ qws, u16* __restrict__ kws, u16* __restrict__ vtws)
{
    __shared__ alignas(16) u16 smem[128 * TP];   // 34816 B; As/Bs alias the front
    u16* As = smem;            // x tile   128x64
    u16* Bs = smem + 8192;     // W tile   128x64

    const int m0 = blockIdx.x * 128;         // x-row tile
    const int n0 = blockIdx.y * 128;         // col tile over 1536
    const int tid  = threadIdx.x;
    const int w    = tid >> 6;
    const int lane = tid & 63;
    const int quad = lane >> 4;
    const int l16  = lane & 15;
    const int wm = w & 1, wn = w >> 1;

    const int sec = n0 >> 9;                 // 0=Q 1=K 2=V
    const int oc0 = n0 & 511;
    const u16*   Wm = (sec == 0) ? Wq : (sec == 1 ? Wk : Wv);
    const float* bb = (sec == 0) ? bq : (sec == 1 ? bk : bv);

    const int xb = (sec < 2) ? wn : wm;      // x-row fragment base
    const int wb = (sec < 2) ? wm : wn;      // W-row fragment base

    f32x4 acc[4][4] = {};

    for (int kb = 0; kb < 8; ++kb) {
#pragma unroll
        for (int it = 0; it < 4; ++it) {
            const int s   = it * 256 + tid;
            const int row = s >> 3;
            const int cb  = s & 7;
            const int gcol = kb * 64 + (((cb ^ (row & 7))) << 3);
            gll16(x  + (m0  + row) * 512 + gcol, &As[s * 8]);
            gll16(Wm + (oc0 + row) * 512 + gcol, &Bs[s * 8]);
        }
        __syncthreads();

#pragma unroll
        for (int ks = 0; ks < 2; ++ks) {
            bf16x8 xf[4], wf[4];
#pragma unroll
            for (int t = 0; t < 4; ++t) {
                const int xrow = xb * 64 + t * 16 + l16;
                const int wrow = wb * 64 + t * 16 + l16;
                xf[t] = *(const bf16x8*)&As[xrow * 64 + (((ks * 4 + quad) ^ (xrow & 7)) << 3)];
                wf[t] = *(const bf16x8*)&Bs[wrow * 64 + (((ks * 4 + quad) ^ (wrow & 7)) << 3)];
            }
            if (sec < 2) {
#pragma unroll
                for (int tm = 0; tm < 4; ++tm)
#pragma unroll
                    for (int tn = 0; tn < 4; ++tn)
                        acc[tm][tn] = MFMA(wf[tm], xf[tn], acc[tm][tn]);  // C row=d, col=s
            } else {
#pragma unroll
                for (int tm = 0; tm < 4; ++tm)
#pragma unroll
                    for (int tn = 0; tn < 4; ++tn)
                        acc[tm][tn] = MFMA(xf[tm], wf[tn], acc[tm][tn]);  // C row=s, col=d
            }
        }
        __syncthreads();
    }

    if (sec < 2) {
        // ---- Q/K epilogue: C row = head-dim, col = s. rope fully in-register ----
#pragma unroll
        for (int tm = 0; tm < 4; ++tm) {
            const int dls = wm * 64 + tm * 16 + quad * 4;         // local d base (mult of 4)
            const float4 bv4 = *(const float4*)&bb[oc0 + dls];
            const int pbase = ((oc0 + dls) & 63) >> 1;            // rope pair idx (even)
#pragma unroll
            for (int tn = 0; tn < 4; ++tn) {
                const int sl = wn * 64 + tn * 16 + l16;           // local s
                const int sg = (m0 + sl) & 2047;                  // seq pos
                const float4 cs = *(const float4*)&cstf[sg * 64 + pbase * 2]; // c0,s0,c1,s1
                const float v0 = acc[tm][tn][0] + bv4.x;
                const float v1 = acc[tm][tn][1] + bv4.y;
                const float v2 = acc[tm][tn][2] + bv4.z;
                const float v3 = acc[tm][tn][3] + bv4.w;
                const float r0 = v0 * cs.x - v1 * cs.y;
                const float r1 = v1 * cs.x + v0 * cs.y;
                const float r2 = v2 * cs.z - v3 * cs.w;
                const float r3 = v3 * cs.z + v2 * cs.w;
                u32x2 pv = { pk_bf16(r0, r1), pk_bf16(r2, r3) };
                *(u32x2*)&smem[sl * TP + dls] = pv;
            }
        }
        __syncthreads();
        u16* dst0 = (sec == 0) ? qws : kws;
#pragma unroll
        for (int i = 0; i < 8; ++i) {
            const int c   = i * 256 + tid;       // [0, 2048)
            const int sl  = c >> 4;              // local s row
            const int d8  = (c & 15) * 8;        // 8-dim chunk
            const int gcol = oc0 + d8;
            const int hh  = gcol >> 6;
            const int dh  = gcol & 63;
            const int sgl = m0 + sl;
            const int bi  = sgl >> 11;
            const int s   = sgl & 2047;
            u16* dst = dst0 + (size_t)(bi * NHEADS + hh) * (SEQ * HEADDIM)
                            + (size_t)s * HEADDIM + dh;
            *(bf16x8*)dst = *(const bf16x8*)&smem[sl * TP + d8];
        }
    } else {
        // ---- V epilogue: C row = s, col = out-col d. LDS transpose T[d][s] ----
#pragma unroll
        for (int tm = 0; tm < 4; ++tm) {
            const int row_l = wm * 64 + tm * 16 + quad * 4;      // local s rows
#pragma unroll
            for (int tn = 0; tn < 4; ++tn) {
                const int col_l = wn * 64 + tn * 16 + l16;       // local out-col
                const float bval = bb[oc0 + col_l];
                u32x2 pv = { pk_bf16(acc[tm][tn][0] + bval, acc[tm][tn][1] + bval),
                             pk_bf16(acc[tm][tn][2] + bval, acc[tm][tn][3] + bval) };
                *(u32x2*)&smem[col_l * TP + row_l] = pv;
            }
        }
        __syncthreads();
        const int bi  = m0 >> 11;
        const int sgb = m0 & 2047;
#pragma unroll
        for (int i = 0; i < 8; ++i) {
            const int c    = i * 256 + tid;      // [0, 2048)
            const int col  = c >> 4;             // local out-col
            const int sc8  = (c & 15) * 8;       // s-chunk
            const int gcol = oc0 + col;
            const int hh   = gcol >> 6;
            const int d    = gcol & 63;
            u16* dst = vtws + (size_t)(bi * NHEADS + hh) * (SEQ * HEADDIM)
                            + (size_t)d * SEQ + sgb + sc8;
            *(bf16x8*)dst = *(const bf16x8*)&smem[col * TP + sc8];
        }
    }
}

// ---------------- kernel 2: flash attention, in-block K-split, permlane-P (builtins) ----------------
// grid (32,32) XCD-swizzled (R5: FETCH 72->12 MB). 8 waves: qw = w&3, kg = w>>2.
// Swapped QK^T: MFMA(K,Q) -> P[k][q=l16] lane-local. P -> PV A-frag via the
// permlane swap BUILTINS (R6/R7 used raw inline asm: v_permlane* reading a VGPR
// written by the immediately-preceding VALU op needs mandatory wait states the
// compiler only inserts for the intrinsic form — raw asm read stale registers).
// Mapping (doc semantics, re-verified): S32 vdst.hi-row <-> vsrc.lo-row;
// S16 vdst.{Q1,Q3} <-> vsrc.{Q0,Q2}:
//   s = S32(x, y):  s.x=(x@0,x@1,y@0,y@1)  s.y=(x@2,x@3,y@2,y@3)
//   t = S16(s.x, s.y): t.x=(x@0,x@2,y@0,y@2)=ap.u[0]  t.y=(x@1,x@3,y@1,y@3)=ap.u[2]
// Deletes the 10 KB P tile -> LDS 34304 B -> 4 blocks/CU (R5 was 3+1 phased, 48%).
// Fallback (#if !HAS_PERMLANE): R5's per-wave LDS P tile (known-good).
// (512,6): VGPR cap ~85; (512,8)=64 caused catastrophic spill (R2).
__global__ __launch_bounds__(512, 6) void attn_kernel(
    const u16* __restrict__ qws, const u16* __restrict__ kws,
    const u16* __restrict__ vtl,
    const int* __restrict__ vids, const float* __restrict__ Mws,
    const float* __restrict__ u_same, const float* __restrict__ u_cross,
    u16* __restrict__ attn)
{
    // LDS map (u16 units):
    //   [    0,  8192): K tiles   [grp][buf][32*64]
    //   [ 8192, 16384): V^T tiles [grp][buf][64*32]
    // combine phase aliases the front as float co[64][65] (16640 B).
    __shared__ alignas(16) u16 smem[16384];
#if !HAS_PERMLANE
    __shared__ alignas(16) u16 plsm[8 * 16 * 40];   // per-wave P tiles [16][40]
#endif
    __shared__ int   bidm[2][2][KTILE];
    __shared__ float bmkm[2][2][KTILE];
    __shared__ float comb_li2[2][QTILE];

    // XCD-locality swizzle (bijective; perf-neutral if dispatch mapping differs)
    const int id  = blockIdx.y * 32 + blockIdx.x;
    const int xcd = id & 7;
    const int idx = id >> 3;                  // [0,128)
    const int bh  = xcd * 4 + (idx & 3);
    const int q0  = (idx >> 2) * QTILE;
    const int b   = bh >> 3;
    const int h   = bh & 7;

    const int tid  = threadIdx.x;
    const int w    = tid >> 6;                // 0..7
    const int lane = tid & 63;
    const int quad = lane >> 4;
    const int l16  = lane & 15;
    const int qw   = w & 3;                   // q sub-tile
    const int kg   = w >> 2;                  // k group
    const int tl   = tid & 255;               // thread index within k group

    const float us2 = u_same[h]  * LOG2E;
    const float uc2 = u_cross[h] * LOG2E;
    const size_t tb = (size_t)bh * (SEQ * HEADDIM);

    const int qr = q0 + qw * 16 + l16;
    const bf16x8 aq0 = *(const bf16x8*)(qws + tb + qr * HEADDIM + quad * 8);
    const bf16x8 aq1 = *(const bf16x8*)(qws + tb + qr * HEADDIM + 32 + quad * 8);

    const int vq = vids[b * SEQ + q0 + qw * 16 + l16];   // this lane's q variate id

    float li = 0.f;
    f32x4 o[4] = {};

    // staging geometry (per k group: 256 threads stage one K + one V^T tile)
    const int srow  = tl >> 3;                // K tile row (k), 0..31
    const int scb   = tl & 7;
    const int soff  = ((scb ^ (srow & 7)) << 3);
    const int vrow  = tl >> 2;                // V^T tile row (d), 0..63
    const int vcb   = (tl & 3) ^ ((vrow >> 1) & 3);   // bank-spread swizzle
    const int soffv = (vcb << 3);
    const int kbase = kg * 2 * 2048;          // + cur*2048

    auto stage = [&](int t, int nb) {
        const int k0 = (kg * NKT_G + t) * KTILE;
        gll16(kws + tb + (size_t)(k0 + srow) * HEADDIM + soff,
              &smem[kbase + nb * 2048 + tl * 8]);
        gll16(vtl + tb + (size_t)vrow * SEQ + k0 + soffv,
              &smem[8192 + kbase + nb * 2048 + tl * 8]);
        if (tl < KTILE) {
            gll4(vids + b * SEQ + k0 + tl, &bidm[kg][nb][0]);
            gll4(Mws  + b * SEQ + k0 + tl, &bmkm[kg][nb][0]);
        }
    };

#if !HAS_PERMLANE
    u16* const pw = &plsm[w * 640];           // this wave's P tile [16][40]
#endif

    auto body = [&](const int cur) {   // cur literal at call sites
        const u16* kb_b = &smem[kbase + cur * 2048];
        const u16* vb_b = &smem[8192 + kbase + cur * 2048];
        unsigned x0, x1, y0, y1;       // packed bf16 P words, nt0 (x) / nt1 (y)
#pragma unroll
        for (int nt = 0; nt < 2; ++nt) {
            const int krow = nt * 16 + l16;
            const int r7   = krow & 7;
            const bf16x8 kb0 = *(const bf16x8*)&kb_b[krow * 64 + ((quad ^ r7) << 3)];
            const bf16x8 kb1 = *(const bf16x8*)&kb_b[krow * 64 + ((quad ^ r7 ^ 4) << 3)];
            f32x4 sc = {};
            __builtin_amdgcn_s_setprio(1);
            sc = MFMA(kb0, aq0, sc);   // swapped: C row = k, col = q(l16)
            sc = MFMA(kb1, aq1, sc);
            __builtin_amdgcn_s_setprio(0);
            const int kk = nt * 16 + quad * 4;     // this lane's 4 k rows
            const int4   kv4 = *(const int4*)&bidm[kg][cur][kk];    // broadcast reads
            const float4 mk4 = *(const float4*)&bmkm[kg][cur][kk];  // precomputed M
            const int   kvr[4] = { kv4.x, kv4.y, kv4.z, kv4.w };
            const float mkr[4] = { mk4.x, mk4.y, mk4.z, mk4.w };
            float p[4];
#pragma unroll
            for (int r = 0; r < 4; ++r) {
                const float sel = mkr[r] + ((kvr[r] == vq) ? us2 : uc2);
                p[r] = __builtin_amdgcn_exp2f(fmaf(sc[r], SCL2, sel));
                li += p[r];
            }
            if (nt == 0) { x0 = pk_bf16(p[0], p[1]); x1 = pk_bf16(p[2], p[3]); }
            else         { y0 = pk_bf16(p[0], p[1]); y1 = pk_bf16(p[2], p[3]); }
        }

        union { unsigned u[4]; bf16x8 v; } ap;
#if HAS_PERMLANE
        // builtins return {new_vdst, new_vsrc}; backend handles wait-states
        auto s0 = __builtin_amdgcn_permlane32_swap(x0, y0, false, false);
        auto t0 = __builtin_amdgcn_permlane16_swap(s0[0], s0[1], false, false);
        auto s1 = __builtin_amdgcn_permlane32_swap(x1, y1, false, false);
        auto t1 = __builtin_amdgcn_permlane16_swap(s1[0], s1[1], false, false);
        ap.u[0] = t0[0]; ap.u[1] = t1[0]; ap.u[2] = t0[1]; ap.u[3] = t1[1];
#else
        // R5 fallback: wave-private LDS P tile [16][40], no barrier needed
        u32x2 pv0 = { x0, x1 };
        u32x2 pv1 = { y0, y1 };
        *(u32x2*)&pw[l16 * 40 + quad * 4]      = pv0;
        *(u32x2*)&pw[l16 * 40 + 16 + quad * 4] = pv1;
        ap.v = *(const bf16x8*)&pw[l16 * 40 + quad * 8];
#endif

        __builtin_amdgcn_s_setprio(1);
#pragma unroll
        for (int nt = 0; nt < 4; ++nt) {
            const int vr = nt * 16 + l16;
            const bf16x8 vb0 = *(const bf16x8*)&vb_b[vr * 32 + (((quad ^ ((vr >> 1) & 3))) << 3)];
            o[nt] = MFMA(ap.v, vb0, o[nt]);
        }
        __builtin_amdgcn_s_setprio(0);
    };

    stage(0, 0);
    for (int t = 0; t < NKT_G; t += 2) {
        __syncthreads();
        stage(t + 1, 1);
        body(0);
        __syncthreads();
        if (t + 2 < NKT_G) stage(t + 2, 0);
        body(1);
    }

    // ---- combine the two k-groups' partials through LDS ----
    float liq = li + __shfl_xor(li, 16);
    liq += __shfl_xor(liq, 32);               // full kg-partial row sum, q = l16
    __syncthreads();
    float* co = (float*)smem;                 // [64][65] f32, aliases K/V buffers
    if (quad == 0) comb_li2[kg][qw * 16 + l16] = liq;
    if (kg == 1) {
#pragma unroll
        for (int nt = 0; nt < 4; ++nt)
#pragma unroll
            for (int r = 0; r < 4; ++r)
                co[(qw * 16 + quad * 4 + r) * 65 + nt * 16 + l16] = o[nt][r];
    }
    __syncthreads();
    if (kg == 0) {
#pragma unroll
        for (int r = 0; r < 4; ++r) {
            const int qloc = qw * 16 + quad * 4 + r;
            const float lt = comb_li2[0][qloc] + comb_li2[1][qloc];
            const float inv = 1.0f / lt;
            const int R  = q0 + qloc;
            const int rb = (b * SEQ + R) * DMODEL + h * HEADDIM;
#pragma unroll
            for (int nt = 0; nt < 4; ++nt)
                attn[rb + nt * 16 + l16] =
                    f2bf((o[nt][r] + co[qloc * 65 + nt * 16 + l16]) * inv);
        }
    }
}

// ---------------- kernel 3: output projection (swapped A/B, LDS store, fp32 out) ----------------
__global__ __launch_bounds__(256) void proj_kernel(
    const u16* __restrict__ a, const u16* __restrict__ Wo,
    const float* __restrict__ bo, float* __restrict__ out)
{
    __shared__ alignas(16) u16 psm[132 * 64 * 2];    // 33792 B; As/Bs alias front, Lp aliases all
    u16* As = psm;
    u16* Bs = psm + 8192;
    float* Lp = (float*)psm;                         // 64 x 132 f32 tile

    const int m0 = blockIdx.x * 128;                 // attn-row tile
    const int n0 = blockIdx.y * 128;                 // out-col strip
    const int tid  = threadIdx.x;
    const int w    = tid >> 6;
    const int lane = tid & 63;
    const int quad = lane >> 4;
    const int l16  = lane & 15;
    const int wm = w & 1, wn = w >> 1;               // wm: W-col tile, wn: s tile

    f32x4 acc[4][4] = {};

    for (int kb = 0; kb < 8; ++kb) {
#pragma unroll
        for (int it = 0; it < 4; ++it) {
            const int s   = it * 256 + tid;
            const int row = s >> 3;
            const int cb  = s & 7;
            const int gcol = kb * 64 + (((cb ^ (row & 7))) << 3);
            gll16(a  + (m0 + row) * 512 + gcol, &As[s * 8]);
            gll16(Wo + (n0 + row) * 512 + gcol, &Bs[s * 8]);
        }
        __syncthreads();

#pragma unroll
        for (int ks = 0; ks < 2; ++ks) {
            bf16x8 af[4], wf[4];
#pragma unroll
            for (int t = 0; t < 4; ++t) {
                const int arow = wn * 64 + t * 16 + l16;
                const int wrow = wm * 64 + t * 16 + l16;
                af[t] = *(const bf16x8*)&As[arow * 64 + (((ks * 4 + quad) ^ (arow & 7)) << 3)];
                wf[t] = *(const bf16x8*)&Bs[wrow * 64 + (((ks * 4 + quad) ^ (wrow & 7)) << 3)];
            }
#pragma unroll
            for (int tm = 0; tm < 4; ++tm)
#pragma unroll
                for (int tn = 0; tn < 4; ++tn)
                    acc[tm][tn] = MFMA(wf[tm], af[tn], acc[tm][tn]);  // C row=d, col=s
        }
        __syncthreads();
    }

    // two phases by s-half: waves wn==hph write Lp[s2][d], all threads store coalesced
#pragma unroll
    for (int hph = 0; hph < 2; ++hph) {
        if (wn == hph) {
#pragma unroll
            for (int tm = 0; tm < 4; ++tm) {
                const int dls = wm * 64 + tm * 16 + quad * 4;
                const float4 bv4 = *(const float4*)&bo[n0 + dls];
#pragma unroll
                for (int tn = 0; tn < 4; ++tn) {
                    const int s2 = tn * 16 + l16;            // [0,64)
                    float4 v = { acc[tm][tn][0] + bv4.x, acc[tm][tn][1] + bv4.y,
                                 acc[tm][tn][2] + bv4.z, acc[tm][tn][3] + bv4.w };
                    *(float4*)&Lp[s2 * 132 + dls] = v;
                }
            }
        }
        __syncthreads();
#pragma unroll
        for (int i = 0; i < 8; ++i) {
            const int c  = i * 256 + tid;        // [0,2048)
            const int s2 = c >> 5;               // [0,64)
            const int dq = (c & 31) * 4;         // [0,128)
            float4 v = *(const float4*)&Lp[s2 * 132 + dq];
            *(float4*)&out[(size_t)(m0 + hph * 64 + s2) * 512 + n0 + dq] = v;
        }
        __syncthreads();
    }
}

// ---------------- launch ----------------
extern "C" void kernel_launch(void* const* d_in, const int* in_sizes, int n_in,
                              void* d_out, int out_size, void* d_ws, size_t ws_size,
                              hipStream_t stream) {
    const float* x    = (const float*)d_in[0];
    const int*   vids = (const int*)d_in[1];
    const float* mask = (const float*)d_in[2];
    const float* Wq = (const float*)d_in[3];
    const float* bq = (const float*)d_in[4];
    const float* Wk = (const float*)d_in[5];
    const float* bk = (const float*)d_in[6];
    const float* Wv = (const float*)d_in[7];
    const float* bv = (const float*)d_in[8];
    const float* Wo = (const float*)d_in[9];
    const float* bo = (const float*)d_in[10];
    const float* usame  = (const float*)d_in[11];
    const float* ucross = (const float*)d_in[12];
    float* out = (float*)d_out;

    u16* xbf  = (u16*)d_ws;                 // 8 MB; reused as attention output
    u16* wqbf = xbf + NX;                   // 512 KB each
    u16* wkbf = wqbf + NW;
    u16* wvbf = wkbf + NW;
    u16* wobf = wvbf + NW;
    float2* cst = (float2*)(wobf + NW);     // 512 KB
    float*  Mws = (float*)(cst + SEQ * 32); // 32 KB mask bias
    u16* qws  = (u16*)(Mws + BATCH * SEQ);  // 8 MB each
    u16* kws  = qws + (size_t)BATCH * NHEADS * SEQ * HEADDIM;
    u16* vtws = kws + (size_t)BATCH * NHEADS * SEQ * HEADDIM;
    u16* attn = xbf;

    cvt_rope_kernel<<<(NCVT4 + NCST4 + NMSK4 + 255) / 256, 256, 0, stream>>>(
        x, Wq, Wk, Wv, Wo, mask, xbf, wqbf, wkbf, wvbf, wobf, cst, Mws);

    dim3 g1(MTOT / 128, 3 * DMODEL / 128);  // 64 x 12
    qkv_kernel<<<g1, 256, 0, stream>>>(xbf, wqbf, bq, wkbf, bk, wvbf, bv,
                                       (const float*)cst, qws, kws, vtws);

    dim3 g2(SEQ / QTILE, BATCH * NHEADS);   // 32 x 32
    attn_kernel<<<g2, 512, 0, stream>>>(qws, kws, vtws, vids, Mws,
                                        usame, ucross, attn);

    dim3 g3(MTOT / 128, DMODEL / 128);      // 64 x 4
    proj_kernel<<<g3, 256, 0, stream>>>(attn, wobf, bo, out);
}